// Round 7
// baseline (511.199 us; speedup 1.0000x reference)
//
#include <hip/hip_runtime.h>

typedef unsigned short u16;
typedef __attribute__((ext_vector_type(8))) short short8;
typedef __attribute__((ext_vector_type(4))) float float4v;

#define MFMA_BF16(a, b, c) __builtin_amdgcn_mfma_f32_16x16x32_bf16((a), (b), (c), 0, 0, 0)

#define B_ 4
#define S_ 2048
#define D_ 1024
#define H_ 8
#define DH_ 128
#define DFF_ 4096
#define EPS_ 1e-5f
#define ROWS_ (B_ * S_)   // 8192
#define CSCALE_ 0.12751672939502f  // (1/sqrt(128)) * log2(e), folded into Q

__device__ __forceinline__ u16 f2bf(float f) {
  union { float f; unsigned u; } x; x.f = f;
  unsigned r = x.u + 0x7fffu + ((x.u >> 16) & 1u);
  return (u16)(r >> 16);
}

typedef __attribute__((address_space(1))) const unsigned int guint;
typedef __attribute__((address_space(3))) unsigned int luint;
__device__ __forceinline__ void gl2lds16(const u16* g, u16* l) {
  // each lane: 16B from its own g -> wave-uniform lds base + lane*16
  __builtin_amdgcn_global_load_lds((guint*)g, (luint*)l, 16, 0, 0);
}

// ---------------- cast fp32 -> bf16 (layout preserved) ----------------
__global__ void cast_bf16_kernel(const float* __restrict__ in, u16* __restrict__ out, int n4) {
  int i = blockIdx.x * blockDim.x + threadIdx.x;
  int stride = gridDim.x * blockDim.x;
  for (; i < n4; i += stride) {
    float4 v = ((const float4*)in)[i];
    ushort4 u;
    u.x = f2bf(v.x); u.y = f2bf(v.y); u.z = f2bf(v.z); u.w = f2bf(v.w);
    ((ushort4*)out)[i] = u;
  }
}

// ---------- cast+transpose fp32 [K][N] -> bf16 [N][K] (weights) ----------
__global__ void transpose_cast_kernel(const float* __restrict__ in, u16* __restrict__ out,
                                      int K, int N) {
  __shared__ float t[32][33];
  int k0 = blockIdx.x * 32, n0 = blockIdx.y * 32;
  int tx = threadIdx.x & 31, ty = threadIdx.x >> 5;  // 32x8 threads
  #pragma unroll
  for (int i = 0; i < 4; ++i)
    t[ty + 8 * i][tx] = in[(size_t)(k0 + ty + 8 * i) * N + n0 + tx];
  __syncthreads();
  #pragma unroll
  for (int i = 0; i < 4; ++i)
    out[(size_t)(n0 + ty + 8 * i) * K + k0 + tx] = f2bf(t[tx][ty + 8 * i]);
}

// ============== bf16 MFMA GEMM, 256x256 tile, 8-phase schedule ==============
// (FFN1: grid 32x16 = 512 blocks; 1 block/CU by LDS, 2 rounds)
// C[M,N] = A[M,K] @ Bt[N,K]^T.  512 thr = 8 waves (2M x 4N); per-wave 128x64.
// MODE 2: +bias, relu, bf16 out.
template <int MODE>
__global__ __launch_bounds__(512, 2) void gemm256_kernel(
    const u16* __restrict__ A, const u16* __restrict__ Bt,
    const int M, const int N, const int K,
    float* __restrict__ outF, u16* __restrict__ outH, const float* __restrict__ bias,
    u16* __restrict__ qo, u16* __restrict__ ko, u16* __restrict__ vo) {
  extern __shared__ u16 smem[];
  u16* At  = smem;                  // [2][256][64] permuted rows, swizzled chunks
  u16* Bts = smem + 2 * 256 * 64;   // [2][256][64] linear rows, swizzled chunks
  const int tid = threadIdx.x;
  const int lane = tid & 63, wave = tid >> 6;
  const int quad = lane >> 4, r16 = lane & 15;
  const int halfw = wave >> 2;          // output row half (0/1)
  const int wn = (wave & 3) * 64;       // output col offset in tile
  const int m0 = blockIdx.x * 256, n0 = blockIdx.y * 256;
  const int NT = K >> 6;

  const int rowin = wave * 8 + (lane >> 3);   // 0..63 within unit
  const int sc = lane & 7;
  const int shalf = rowin >> 5, srr = rowin & 31;

  const u16* Asrc[4];
  const u16* Bsrc[4];
  #pragma unroll
  for (int u = 0; u < 4; ++u) {
    const int ra = shalf * 128 + u * 32 + srr;   // logical A row of unit u
    Asrc[u] = A + (size_t)(m0 + ra) * K + (sc ^ (ra & 7)) * 8;
    const int rb = u * 64 + rowin;               // logical B row of unit u
    Bsrc[u] = Bt + (size_t)(n0 + rb) * K + (sc ^ (rb & 7)) * 8;
  }

  float4v acc[8][4];
  #pragma unroll
  for (int i = 0; i < 8; ++i)
    #pragma unroll
    for (int j = 0; j < 4; ++j) acc[i][j] = (float4v)0.0f;

#define STAGE_A(t, u) gl2lds16(Asrc[u] + (t) * 64, At  + ((t) & 1) * 16384 + (u) * 4096 + wave * 512)
#define STAGE_B(t, u) gl2lds16(Bsrc[u] + (t) * 64, Bts + ((t) & 1) * 16384 + (u) * 4096 + wave * 512)

  STAGE_B(0, 0); STAGE_B(0, 1); STAGE_B(0, 2); STAGE_B(0, 3);
  STAGE_A(0, 0); STAGE_A(0, 1); STAGE_A(0, 2); STAGE_A(0, 3);
  if (NT > 1) {
    STAGE_B(1, 0); STAGE_B(1, 1); STAGE_B(1, 2); STAGE_B(1, 3);
    STAGE_A(1, 0); STAGE_A(1, 1);
    asm volatile("s_waitcnt vmcnt(6)" ::: "memory");
  } else {
    asm volatile("s_waitcnt vmcnt(0)" ::: "memory");
  }
  __builtin_amdgcn_s_barrier();

  for (int kt = 0; kt < NT; ++kt) {
    const u16* Ab = At + (kt & 1) * 16384;
    const u16* Bb = Bts + (kt & 1) * 16384;
    short8 bfr[4][2];
    #pragma unroll
    for (int q = 0; q < 4; ++q) {
      if (q == 0) {
        #pragma unroll
        for (int j = 0; j < 4; ++j)
          #pragma unroll
          for (int s = 0; s < 2; ++s)
            bfr[j][s] = *(const short8*)(Bb + (wn + j * 16 + r16) * 64 +
                                         (((s * 4 + quad) ^ (r16 & 7)) * 8));
      }
      short8 af[2][2];
      #pragma unroll
      for (int di = 0; di < 2; ++di)
        #pragma unroll
        for (int s = 0; s < 2; ++s)
          af[di][s] = *(const short8*)(Ab + (q * 64 + halfw * 32 + di * 16 + r16) * 64 +
                                       (((s * 4 + quad) ^ (r16 & 7)) * 8));
      if (q == 0)      { if (kt + 1 < NT) { STAGE_A(kt + 1, 2); STAGE_A(kt + 1, 3); } }
      else if (q == 1) { if (kt + 2 < NT) { STAGE_B(kt + 2, 0); STAGE_B(kt + 2, 1); } }
      else if (q == 2) { if (kt + 2 < NT) { STAGE_B(kt + 2, 2); STAGE_B(kt + 2, 3); } }
      else             { if (kt + 2 < NT) { STAGE_A(kt + 2, 0); STAGE_A(kt + 2, 1); } }
      __builtin_amdgcn_s_barrier();
      asm volatile("s_waitcnt lgkmcnt(0)" ::: "memory");
      __builtin_amdgcn_s_setprio(1);
      #pragma unroll
      for (int j = 0; j < 4; ++j) {
        acc[2 * q][j]     = MFMA_BF16(af[0][0], bfr[j][0], acc[2 * q][j]);
        acc[2 * q][j]     = MFMA_BF16(af[0][1], bfr[j][1], acc[2 * q][j]);
        acc[2 * q + 1][j] = MFMA_BF16(af[1][0], bfr[j][0], acc[2 * q + 1][j]);
        acc[2 * q + 1][j] = MFMA_BF16(af[1][1], bfr[j][1], acc[2 * q + 1][j]);
      }
      __builtin_amdgcn_s_setprio(0);
      if (q == 3) {
        if (kt + 2 < NT)      { asm volatile("s_waitcnt vmcnt(6)" ::: "memory"); }
        else if (kt + 1 < NT) { asm volatile("s_waitcnt vmcnt(0)" ::: "memory"); }
      }
      __builtin_amdgcn_s_barrier();
    }
  }
#undef STAGE_A
#undef STAGE_B

  #pragma unroll
  for (int i = 0; i < 8; ++i) {
    const int rowb = m0 + halfw * 128 + i * 16 + quad * 4;
    #pragma unroll
    for (int j = 0; j < 4; ++j) {
      const int col = n0 + wn + j * 16 + r16;
      #pragma unroll
      for (int rg = 0; rg < 4; ++rg) {
        float val = acc[i][j][rg];
        const int r = rowb + rg;
        if (MODE == 2) {
          val += bias[col];
          val = fmaxf(val, 0.0f);
          outH[(size_t)r * N + col] = f2bf(val);
        } else {
          outF[(size_t)r * N + col] = val;
        }
      }
    }
  }
}

// ============ bf16 MFMA GEMM, 256x128 tile, phase-pipelined ============
// 512 thr = 8 waves (4M x 2N); per-wave 64x64 output, acc[4][4].
// BK=64, dbuf LDS = 96 KiB.  2 phases/K-tile, 16 MFMA each.
// MODE 0: scatter q/k bf16 + V DIRECTLY TRANSPOSED into vT[bh][dh][s];
// MODE 1: fp32; MODE 3: +bias fp32.
template <int MODE>
__global__ __launch_bounds__(512, 2) void gemm256x128_kernel(
    const u16* __restrict__ A, const u16* __restrict__ Bt,
    const int M, const int N, const int K,
    float* __restrict__ outF, u16* __restrict__ outH, const float* __restrict__ bias,
    u16* __restrict__ qo, u16* __restrict__ ko, u16* __restrict__ vo) {
  extern __shared__ u16 smem[];
  u16* At  = smem;                  // [2][256][64]
  u16* Bts = smem + 2 * 256 * 64;   // [2][128][64]
  const int tid = threadIdx.x;
  const int lane = tid & 63, wave = tid >> 6;
  const int quad = lane >> 4, r16 = lane & 15;
  const int w64 = wave >> 1;            // output row quarter (0..3)
  const int wn = (wave & 1) * 64;       // output col offset in tile
  const int m0 = blockIdx.x * 256, n0 = blockIdx.y * 128;
  const int NT = K >> 6;

  const int rowin = wave * 8 + (lane >> 3);   // 0..63 within 64-row unit
  const int sc = lane & 7;

  const u16* Asrc[4];
  const u16* Bsrc[2];
  #pragma unroll
  for (int u = 0; u < 4; ++u) {
    // logical A row of unit u at this thread's slot
    const int ra = ((u & 1) * 2 + (rowin >> 5)) * 64 + (u >> 1) * 32 + (rowin & 31);
    Asrc[u] = A + (size_t)(m0 + ra) * K + (sc ^ (ra & 7)) * 8;
  }
  #pragma unroll
  for (int u = 0; u < 2; ++u) {
    const int rb = u * 64 + rowin;
    Bsrc[u] = Bt + (size_t)(n0 + rb) * K + (sc ^ (rb & 7)) * 8;
  }

  float4v acc[4][4];
  #pragma unroll
  for (int i = 0; i < 4; ++i)
    #pragma unroll
    for (int j = 0; j < 4; ++j) acc[i][j] = (float4v)0.0f;

#define STAGE_A(t, u) gl2lds16(Asrc[u] + (t) * 64, At  + ((t) & 1) * 16384 + (u) * 4096 + wave * 512)
#define STAGE_B(t, u) gl2lds16(Bsrc[u] + (t) * 64, Bts + ((t) & 1) * 8192 + (u) * 4096 + wave * 512)

  // prologue: tile0 all 6 units; tile1 B0,B1,A0,A1 -> wait tile0 landed
  STAGE_B(0, 0); STAGE_B(0, 1); STAGE_A(0, 0); STAGE_A(0, 1);
  STAGE_A(0, 2); STAGE_A(0, 3);
  STAGE_B(1, 0); STAGE_B(1, 1); STAGE_A(1, 0); STAGE_A(1, 1);
  asm volatile("s_waitcnt vmcnt(6)" ::: "memory");
  __builtin_amdgcn_s_barrier();

  for (int kt = 0; kt < NT; ++kt) {
    const u16* Ab = At + (kt & 1) * 16384;
    const u16* Bb = Bts + (kt & 1) * 8192;
    // ---- phase 0: rows w64*64 + [0,32) ----
    short8 bfr[4][2];
    #pragma unroll
    for (int j = 0; j < 4; ++j)
      #pragma unroll
      for (int s = 0; s < 2; ++s)
        bfr[j][s] = *(const short8*)(Bb + (wn + j * 16 + r16) * 64 +
                                     (((s * 4 + quad) ^ (r16 & 7)) * 8));
    {
      short8 af[2][2];
      #pragma unroll
      for (int di = 0; di < 2; ++di)
        #pragma unroll
        for (int s = 0; s < 2; ++s)
          af[di][s] = *(const short8*)(Ab + (w64 * 32 + di * 16 + r16) * 64 +
                                       (((s * 4 + quad) ^ (r16 & 7)) * 8));
      if (kt + 1 < NT) { STAGE_A(kt + 1, 2); STAGE_A(kt + 1, 3); }
      __builtin_amdgcn_s_barrier();
      asm volatile("s_waitcnt lgkmcnt(0)" ::: "memory");
      __builtin_amdgcn_s_setprio(1);
      #pragma unroll
      for (int j = 0; j < 4; ++j) {
        acc[0][j] = MFMA_BF16(af[0][0], bfr[j][0], acc[0][j]);
        acc[0][j] = MFMA_BF16(af[0][1], bfr[j][1], acc[0][j]);
        acc[1][j] = MFMA_BF16(af[1][0], bfr[j][0], acc[1][j]);
        acc[1][j] = MFMA_BF16(af[1][1], bfr[j][1], acc[1][j]);
      }
      __builtin_amdgcn_s_setprio(0);
      if (kt + 1 < NT) { asm volatile("s_waitcnt vmcnt(6)" ::: "memory"); }
      else             { asm volatile("s_waitcnt vmcnt(0)" ::: "memory"); }
      __builtin_amdgcn_s_barrier();
    }
    // ---- phase 1: rows w64*64 + [32,64) ----
    {
      short8 af[2][2];
      #pragma unroll
      for (int di = 0; di < 2; ++di)
        #pragma unroll
        for (int s = 0; s < 2; ++s)
          af[di][s] = *(const short8*)(Ab + (128 + w64 * 32 + di * 16 + r16) * 64 +
                                       (((s * 4 + quad) ^ (r16 & 7)) * 8));
      if (kt + 2 < NT) {
        STAGE_B(kt + 2, 0); STAGE_B(kt + 2, 1);
        STAGE_A(kt + 2, 0); STAGE_A(kt + 2, 1);
      }
      __builtin_amdgcn_s_barrier();
      asm volatile("s_waitcnt lgkmcnt(0)" ::: "memory");
      __builtin_amdgcn_s_setprio(1);
      #pragma unroll
      for (int j = 0; j < 4; ++j) {
        acc[2][j] = MFMA_BF16(af[0][0], bfr[j][0], acc[2][j]);
        acc[2][j] = MFMA_BF16(af[0][1], bfr[j][1], acc[2][j]);
        acc[3][j] = MFMA_BF16(af[1][0], bfr[j][0], acc[3][j]);
        acc[3][j] = MFMA_BF16(af[1][1], bfr[j][1], acc[3][j]);
      }
      __builtin_amdgcn_s_setprio(0);
      if (kt + 1 < NT) {
        if (kt + 2 < NT) { asm volatile("s_waitcnt vmcnt(6)" ::: "memory"); }
        else             { asm volatile("s_waitcnt vmcnt(2)" ::: "memory"); }
      }
      __builtin_amdgcn_s_barrier();
    }
  }
#undef STAGE_A
#undef STAGE_B

  // epilogue: D row = quad*4+rg within 16-row frag; col = r16 within 16-col frag
  #pragma unroll
  for (int i = 0; i < 4; ++i) {
    const int rowb = m0 + w64 * 64 + i * 16 + quad * 4;
    #pragma unroll
    for (int j = 0; j < 4; ++j) {
      const int col = n0 + wn + j * 16 + r16;
      #pragma unroll
      for (int rg = 0; rg < 4; ++rg) {
        float val = acc[i][j][rg];
        const int r = rowb + rg;
        if (MODE == 0) {
          const int part = col >> 10, cc = col & 1023;
          const int h = cc >> 7, dh = cc & 127;
          const int b = r >> 11, s = r & 2047;
          if (part == 0) {
            qo[((size_t)(b * H_ + h) * S_ + s) * DH_ + dh] = f2bf(val * CSCALE_);
          } else if (part == 1) {
            ko[((size_t)(b * H_ + h) * S_ + s) * DH_ + dh] = f2bf(val);
          } else {
            // V directly transposed: vT[bh][dh][s] (4 rg values = consecutive s)
            vo[((size_t)(b * H_ + h) * DH_ + dh) * S_ + s] = f2bf(val);
          }
        } else if (MODE == 1) {
          outF[(size_t)r * N + col] = val;
        } else {
          val += bias[col];
          outF[(size_t)r * N + col] = val;
        }
      }
    }
  }
}

// ---------------- flash causal attention (S^T formulation) ----------------
// Q (pre-scaled), K: [bh][S][DH] bf16; Vt: [bh][DH][S] bf16; O: [rows][D] bf16.
// 1024 single-qb blocks; decode keeps 4 heads per XCD (K/V L2-resident) and
// orders qb descending within each XCD (LPT: long blocks start first).
// 3 blocks/CU (45KB LDS). Async-STAGE (T14) + defer-max (T13, THR=8 log2).
__global__ __launch_bounds__(256) void attn_kernel(
    const u16* __restrict__ Q, const u16* __restrict__ Kg,
    const u16* __restrict__ Vtg, u16* __restrict__ O) {
  __shared__ u16 Ks[64][136];     // [key][d]
  __shared__ u16 Vt[128][72];     // [d][key]
  __shared__ u16 Pw[4][16][72];   // per-wave P [q][key]
  const int tid = threadIdx.x;
  const int lane = tid & 63, wave = tid >> 6;
  const int quad = lane >> 4, r16 = lane & 15;
  const int id = blockIdx.x;                        // 0..1023
  const int bh = (id & 7) * 4 + ((id >> 3) & 3);    // 4 heads per XCD
  const int qb = 31 - (id >> 5);                    // long blocks dispatched first
  const size_t base = (size_t)bh * S_ * DH_;
  const size_t vtb = (size_t)bh * DH_ * S_;
  const int b = bh >> 3, h = bh & 7;

  // hoisted staging addresses
  const u16* kg0 = Kg + base + (size_t)(tid >> 4) * DH_ + (tid & 15) * 8;
  u16* ksl = &Ks[tid >> 4][(tid & 15) * 8];
  const u16* vg0 = Vtg + vtb + (size_t)(tid >> 3) * S_ + (tid & 7) * 8;
  u16* vtl = &Vt[tid >> 3][(tid & 7) * 8];

  short8 rk[4], rv[4];
#define LOADKV(kb_)                                                        \
  do {                                                                     \
    _Pragma("unroll")                                                      \
    for (int i_ = 0; i_ < 4; ++i_)                                         \
      rk[i_] = *(const short8*)(kg0 + (size_t)((kb_) * 64 + i_ * 16) * DH_); \
    _Pragma("unroll")                                                      \
    for (int i_ = 0; i_ < 4; ++i_)                                         \
      rv[i_] = *(const short8*)(vg0 + (size_t)i_ * 32 * S_ + (kb_) * 64);  \
  } while (0)

  const int qr = qb * 64 + wave * 16 + r16;  // this lane's q-row (as B-col)

  // Q fragment: B-operand layout B[k=quad*8+j][n=r16] == Q[q=r16][k] regs
  short8 aq[4];
  #pragma unroll
  for (int ks = 0; ks < 4; ++ks)
    aq[ks] = *(const short8*)(Q + base + (size_t)qr * DH_ + ks * 32 + quad * 8);

  float4v acco[8];
  #pragma unroll
  for (int i = 0; i < 8; ++i) acco[i] = (float4v)0.0f;
  float m_q = -1e30f, l_q = 0.0f;  // per q=r16, replicated across quads

  LOADKV(0);  // prefetch tile 0

  for (int kb = 0; kb <= qb; ++kb) {
    __syncthreads();   // prior iter's LDS reads done before overwrite
    // ds_write staged regs (compiler inserts vmcnt wait on rk/rv here)
    #pragma unroll
    for (int i = 0; i < 4; ++i) *(short8*)(ksl + i * 16 * 136) = rk[i];
    #pragma unroll
    for (int i = 0; i < 4; ++i) *(short8*)(vtl + i * 32 * 72) = rv[i];
    __syncthreads();
    if (kb < qb) LOADKV(kb + 1);  // prefetch next tile; latency hides under compute

    // S^T tile: rows = keys (64), cols = q (16/wave). A = K, B = Qfrag.
    float4v accs[4];
    #pragma unroll
    for (int t = 0; t < 4; ++t) accs[t] = (float4v)0.0f;
    #pragma unroll
    for (int ks = 0; ks < 4; ++ks) {
      #pragma unroll
      for (int t = 0; t < 4; ++t) {
        short8 ak = *(const short8*)&Ks[t * 16 + r16][ks * 32 + quad * 8];
        accs[t] = MFMA_BF16(ak, aq[ks], accs[t]);
      }
    }
    // causal mask on diagonal block; scores already in log2 domain
    if (kb == qb) {
      #pragma unroll
      for (int t = 0; t < 4; ++t)
        #pragma unroll
        for (int rg = 0; rg < 4; ++rg) {
          int kc = kb * 64 + t * 16 + quad * 4 + rg;
          if (kc > qr) accs[t][rg] = -1e30f;
        }
    }
    // online softmax: lane owns q=r16; 16 local scores + 2 shfl (quads)
    float mv = accs[0][0];
    #pragma unroll
    for (int t = 0; t < 4; ++t)
      #pragma unroll
      for (int rg = 0; rg < 4; ++rg) mv = fmaxf(mv, accs[t][rg]);
    mv = fmaxf(mv, __shfl_xor(mv, 16));
    mv = fmaxf(mv, __shfl_xor(mv, 32));
    // defer-max: if tile max is within THR of running max, keep m_q (skip
    // O-rescale; P bounded by 2^8, fp32-safe). Wave-uniform branch.
    const bool nore = __all(mv <= m_q + 8.0f) != 0;
    const float mnew = nore ? m_q : fmaxf(m_q, mv);
    float alpha = 1.0f;
    if (!nore) alpha = __builtin_amdgcn_exp2f(m_q - mnew);
    float s0 = 0.0f;
    #pragma unroll
    for (int t = 0; t < 4; ++t)
      #pragma unroll
      for (int rg = 0; rg < 4; ++rg) {
        float p = __builtin_amdgcn_exp2f(accs[t][rg] - mnew);
        accs[t][rg] = p;
        s0 += p;
      }
    s0 += __shfl_xor(s0, 16);
    s0 += __shfl_xor(s0, 32);
    l_q = nore ? (l_q + s0) : (l_q * alpha + s0);
    m_q = mnew;

    // P^T (C-layout: 4 consecutive keys/lane) -> Pw[q][key], packed b64
    #pragma unroll
    for (int t = 0; t < 4; ++t) {
      union { float f; unsigned u; } c0, c1, c2, c3;
      c0.f = accs[t][0]; c1.f = accs[t][1]; c2.f = accs[t][2]; c3.f = accs[t][3];
      uint2 pk;
      pk.x = ((c0.u + 0x8000u) >> 16) | ((c1.u + 0x8000u) & 0xffff0000u);
      pk.y = ((c2.u + 0x8000u) >> 16) | ((c3.u + 0x8000u) & 0xffff0000u);
      *(uint2*)&Pw[wave][r16][t * 16 + quad * 4] = pk;
    }
    if (!nore) {
      // rescale O by alpha of its rows q = quad*4+rg
      float al[4];
      #pragma unroll
      for (int rg = 0; rg < 4; ++rg) al[rg] = __shfl(alpha, quad * 4 + rg);
      #pragma unroll
      for (int nt = 0; nt < 8; ++nt)
        #pragma unroll
        for (int rg = 0; rg < 4; ++rg) acco[nt][rg] *= al[rg];
    }
    asm volatile("s_waitcnt lgkmcnt(0)" ::: "memory");
    // O += P @ V
    #pragma unroll
    for (int ks2 = 0; ks2 < 2; ++ks2) {
      short8 ap = *(const short8*)&Pw[wave][r16][ks2 * 32 + quad * 8];
      #pragma unroll
      for (int nt = 0; nt < 8; ++nt) {
        short8 bv = *(const short8*)&Vt[nt * 16 + r16][ks2 * 32 + quad * 8];
        acco[nt] = MFMA_BF16(ap, bv, acco[nt]);
      }
    }
  }

  // epilogue: O rows q=quad*4+rg, cols d=nt*16+r16
  float lr[4];
  #pragma unroll
  for (int rg = 0; rg < 4; ++rg) lr[rg] = __shfl(l_q, quad * 4 + rg);
  const int sbase = qb * 64 + wave * 16 + quad * 4;
  #pragma unroll
  for (int nt = 0; nt < 8; ++nt)
    #pragma unroll
    for (int rg = 0; rg < 4; ++rg) {
      float val = acco[nt][rg] / lr[rg];
      O[((size_t)(b * S_ + sbase + rg)) * D_ + h * DH_ + nt * 16 + r16] = f2bf(val);
    }
#undef LOADKV
}

// ---------- layernorm: y = LN(a [+ a2] + res) * g + be ----------
__global__ __launch_bounds__(256) void ln_kernel(
    const float* __restrict__ a, const float* __restrict__ a2,
    const float* __restrict__ res,
    const float* __restrict__ g, const float* __restrict__ be,
    float* __restrict__ xf, u16* __restrict__ xb) {
  __shared__ float red[8];
  const int row = blockIdx.x, tid = threadIdx.x;
  const float4 va = ((const float4*)(a + (size_t)row * D_))[tid];
  const float4 vr = ((const float4*)(res + (size_t)row * D_))[tid];
  float4 v;
  v.x = va.x + vr.x; v.y = va.y + vr.y; v.z = va.z + vr.z; v.w = va.w + vr.w;
  if (a2) {
    const float4 v2 = ((const float4*)(a2 + (size_t)row * D_))[tid];
    v.x += v2.x; v.y += v2.y; v.z += v2.z; v.w += v2.w;
  }
  float s = v.x + v.y + v.z + v.w;
  float q = v.x * v.x + v.y * v.y + v.z * v.z + v.w * v.w;
  #pragma unroll
  for (int m = 1; m < 64; m <<= 1) {
    s += __shfl_xor(s, m);
    q += __shfl_xor(q, m);
  }
  const int wave = tid >> 6, lane = tid & 63;
  if (lane == 0) { red[wave] = s; red[4 + wave] = q; }
  __syncthreads();
  s = red[0] + red[1] + red[2] + red[3];
  q = red[4] + red[5] + red[6] + red[7];
  const float mu = s * (1.0f / D_);
  const float var = q * (1.0f / D_) - mu * mu;
  const float inv = rsqrtf(var + EPS_);
  const float4 gg = ((const float4*)g)[tid];
  const float4 bb = ((const float4*)be)[tid];
  float4 y;
  y.x = (v.x - mu) * inv * gg.x + bb.x;
  y.y = (v.y - mu) * inv * gg.y + bb.y;
  y.z = (v.z - mu) * inv * gg.z + bb.z;
  y.w = (v.w - mu) * inv * gg.w + bb.w;
  ((float4*)(xf + (size_t)row * D_))[tid] = y;
  if (xb) {
    ushort4 u;
    u.x = f2bf(y.x); u.y = f2bf(y.y); u.z = f2bf(y.z); u.w = f2bf(y.w);
    ((ushort4*)(xb + (size_t)row * D_))[tid] = u;
  }
}

extern "C" void kernel_launch(void* const* d_in, const int* in_sizes, int n_in,
                              void* d_out, int out_size, void* d_ws, size_t ws_size,
                              hipStream_t stream) {
  const float* src   = (const float*)d_in[0];
  const float* w_qkv = (const float*)d_in[1];
  const float* w_out = (const float*)d_in[2];
  const float* w1    = (const float*)d_in[3];
  const float* b1    = (const float*)d_in[4];
  const float* w2    = (const float*)d_in[5];
  const float* b2    = (const float*)d_in[6];
  const float* g1    = (const float*)d_in[7];
  const float* be1   = (const float*)d_in[8];
  const float* g2    = (const float*)d_in[9];
  const float* be2   = (const float*)d_in[10];
  float* out = (float*)d_out;

  char* ws = (char*)d_ws;
  size_t off = 0;
  auto alloc = [&](size_t bytes) -> void* {
    void* p = ws + off;
    off += (bytes + 255) & ~(size_t)255;
    return p;
  };
  u16* src_bf = (u16*)alloc((size_t)ROWS_ * D_ * 2);
  u16* wqkvT  = (u16*)alloc((size_t)3 * D_ * D_ * 2);   // [3072][1024]
  u16* woutT  = (u16*)alloc((size_t)D_ * D_ * 2);
  u16* w1T    = (u16*)alloc((size_t)DFF_ * D_ * 2);     // [4096][1024]
  u16* w2T    = (u16*)alloc((size_t)D_ * DFF_ * 2);     // [1024][4096]
  u16* qbuf   = (u16*)alloc((size_t)ROWS_ * D_ * 2);
  u16* kbuf   = (u16*)alloc((size_t)ROWS_ * D_ * 2);
  u16* vT     = (u16*)alloc((size_t)ROWS_ * D_ * 2);    // V already transposed
  u16* obuf   = (u16*)alloc((size_t)ROWS_ * D_ * 2);
  float* proj = (float*)alloc((size_t)ROWS_ * D_ * 4);
  float* xf   = (float*)alloc((size_t)ROWS_ * D_ * 4);
  u16* xb     = (u16*)alloc((size_t)ROWS_ * D_ * 2);
  u16* h1     = qbuf;   // alias: q,k,o dead before FFN1 writes
  float* ff   = proj;   // alias: proj dead after LN1

  const int GSMEM  = 131072;  // 256x256: 2 bufs x (A 32KB + B 32KB)
  const int GSMEM2 = 98304;   // 256x128: 2 bufs x (A 32KB + B 16KB)
  hipFuncSetAttribute((const void*)gemm256_kernel<2>, hipFuncAttributeMaxDynamicSharedMemorySize, GSMEM);
  hipFuncSetAttribute((const void*)gemm256x128_kernel<0>, hipFuncAttributeMaxDynamicSharedMemorySize, GSMEM2);
  hipFuncSetAttribute((const void*)gemm256x128_kernel<1>, hipFuncAttributeMaxDynamicSharedMemorySize, GSMEM2);
  hipFuncSetAttribute((const void*)gemm256x128_kernel<3>, hipFuncAttributeMaxDynamicSharedMemorySize, GSMEM2);

  cast_bf16_kernel<<<2048, 256, 0, stream>>>(src, src_bf, ROWS_ * D_ / 4);
  transpose_cast_kernel<<<dim3(D_ / 32, 3 * D_ / 32), 256, 0, stream>>>(w_qkv, wqkvT, D_, 3 * D_);
  transpose_cast_kernel<<<dim3(D_ / 32, D_ / 32), 256, 0, stream>>>(w_out, woutT, D_, D_);
  transpose_cast_kernel<<<dim3(D_ / 32, DFF_ / 32), 256, 0, stream>>>(w1, w1T, D_, DFF_);
  transpose_cast_kernel<<<dim3(DFF_ / 32, D_ / 32), 256, 0, stream>>>(w2, w2T, DFF_, D_);

  // QKV: N=3072 -> 32x24 = 768 blocks; V written directly transposed
  gemm256x128_kernel<0><<<dim3(ROWS_ / 256, 3 * D_ / 128), 512, GSMEM2, stream>>>(
      src_bf, wqkvT, ROWS_, 3 * D_, D_, nullptr, nullptr, nullptr, qbuf, kbuf, vT);
  // attn: 1024 single-qb blocks, XCD-grouped, LPT order, 3 blocks/CU
  attn_kernel<<<1024, 256, 0, stream>>>(qbuf, kbuf, vT, obuf);
  // out-proj: N=1024 -> 32x8 = 256 blocks
  gemm256x128_kernel<1><<<dim3(ROWS_ / 256, D_ / 128), 512, GSMEM2, stream>>>(
      obuf, woutT, ROWS_, D_, D_, proj, nullptr, nullptr, nullptr, nullptr, nullptr);
  ln_kernel<<<ROWS_, 256, 0, stream>>>(proj, nullptr, src, g1, be1, xf, xb);
  // FFN1: N=4096 -> 256x256 tile: 32x16 = 512 blocks
  gemm256_kernel<2><<<dim3(ROWS_ / 256, DFF_ / 256), 512, GSMEM, stream>>>(
      xb, w1T, ROWS_, DFF_, D_, nullptr, h1, b1, nullptr, nullptr, nullptr);
  // FFN2: N=1024, K=4096 -> 32x8 = 256 blocks (plain, no split-K)
  gemm256x128_kernel<3><<<dim3(ROWS_ / 256, D_ / 128), 512, GSMEM2, stream>>>(
      h1, w2T, ROWS_, D_, DFF_, ff, nullptr, b2, nullptr, nullptr, nullptr);
  ln_kernel<<<ROWS_, 256, 0, stream>>>(ff, nullptr, xf, g2, be2, out, nullptr);
}

// Round 8
// 480.475 us; speedup vs baseline: 1.0639x; 1.0639x over previous
//
#include <hip/hip_runtime.h>

typedef unsigned short u16;
typedef __attribute__((ext_vector_type(8))) short short8;
typedef __attribute__((ext_vector_type(4))) float float4v;

#define MFMA_BF16(a, b, c) __builtin_amdgcn_mfma_f32_16x16x32_bf16((a), (b), (c), 0, 0, 0)

#define B_ 4
#define S_ 2048
#define D_ 1024
#define H_ 8
#define DH_ 128
#define DFF_ 4096
#define EPS_ 1e-5f
#define ROWS_ (B_ * S_)   // 8192
#define CSCALE_ 0.12751672939502f  // (1/sqrt(128)) * log2(e), folded into Q

__device__ __forceinline__ u16 f2bf(float f) {
  union { float f; unsigned u; } x; x.f = f;
  unsigned r = x.u + 0x7fffu + ((x.u >> 16) & 1u);
  return (u16)(r >> 16);
}

typedef __attribute__((address_space(1))) const unsigned int guint;
typedef __attribute__((address_space(3))) unsigned int luint;
__device__ __forceinline__ void gl2lds16(const u16* g, u16* l) {
  // each lane: 16B from its own g -> wave-uniform lds base + lane*16
  __builtin_amdgcn_global_load_lds((guint*)g, (luint*)l, 16, 0, 0);
}

// ---------------- cast fp32 -> bf16 (layout preserved) ----------------
__global__ void cast_bf16_kernel(const float* __restrict__ in, u16* __restrict__ out, int n4) {
  int i = blockIdx.x * blockDim.x + threadIdx.x;
  int stride = gridDim.x * blockDim.x;
  for (; i < n4; i += stride) {
    float4 v = ((const float4*)in)[i];
    ushort4 u;
    u.x = f2bf(v.x); u.y = f2bf(v.y); u.z = f2bf(v.z); u.w = f2bf(v.w);
    ((ushort4*)out)[i] = u;
  }
}

// ---------- cast+transpose fp32 [K][N] -> bf16 [N][K] (weights) ----------
__global__ void transpose_cast_kernel(const float* __restrict__ in, u16* __restrict__ out,
                                      int K, int N) {
  __shared__ float t[32][33];
  int k0 = blockIdx.x * 32, n0 = blockIdx.y * 32;
  int tx = threadIdx.x & 31, ty = threadIdx.x >> 5;  // 32x8 threads
  #pragma unroll
  for (int i = 0; i < 4; ++i)
    t[ty + 8 * i][tx] = in[(size_t)(k0 + ty + 8 * i) * N + n0 + tx];
  __syncthreads();
  #pragma unroll
  for (int i = 0; i < 4; ++i)
    out[(size_t)(n0 + ty + 8 * i) * K + k0 + tx] = f2bf(t[tx][ty + 8 * i]);
}

// ============== bf16 MFMA GEMM, 256x256 tile, 8-phase schedule ==============
// (FFN1: grid 32x16 = 512 blocks)
// C[M,N] = A[M,K] @ Bt[N,K]^T.  512 thr = 8 waves (2M x 4N); per-wave 128x64.
// MODE 2: +bias, relu, bf16 out.
template <int MODE>
__global__ __launch_bounds__(512, 2) void gemm256_kernel(
    const u16* __restrict__ A, const u16* __restrict__ Bt,
    const int M, const int N, const int K,
    float* __restrict__ outF, u16* __restrict__ outH, const float* __restrict__ bias,
    u16* __restrict__ qo, u16* __restrict__ ko, u16* __restrict__ vo) {
  extern __shared__ u16 smem[];
  u16* At  = smem;                  // [2][256][64] permuted rows, swizzled chunks
  u16* Bts = smem + 2 * 256 * 64;   // [2][256][64] linear rows, swizzled chunks
  const int tid = threadIdx.x;
  const int lane = tid & 63, wave = tid >> 6;
  const int quad = lane >> 4, r16 = lane & 15;
  const int halfw = wave >> 2;          // output row half (0/1)
  const int wn = (wave & 3) * 64;       // output col offset in tile
  const int m0 = blockIdx.x * 256, n0 = blockIdx.y * 256;
  const int NT = K >> 6;

  const int rowin = wave * 8 + (lane >> 3);   // 0..63 within unit
  const int sc = lane & 7;
  const int shalf = rowin >> 5, srr = rowin & 31;

  const u16* Asrc[4];
  const u16* Bsrc[4];
  #pragma unroll
  for (int u = 0; u < 4; ++u) {
    const int ra = shalf * 128 + u * 32 + srr;   // logical A row of unit u
    Asrc[u] = A + (size_t)(m0 + ra) * K + (sc ^ (ra & 7)) * 8;
    const int rb = u * 64 + rowin;               // logical B row of unit u
    Bsrc[u] = Bt + (size_t)(n0 + rb) * K + (sc ^ (rb & 7)) * 8;
  }

  float4v acc[8][4];
  #pragma unroll
  for (int i = 0; i < 8; ++i)
    #pragma unroll
    for (int j = 0; j < 4; ++j) acc[i][j] = (float4v)0.0f;

#define STAGE_A(t, u) gl2lds16(Asrc[u] + (t) * 64, At  + ((t) & 1) * 16384 + (u) * 4096 + wave * 512)
#define STAGE_B(t, u) gl2lds16(Bsrc[u] + (t) * 64, Bts + ((t) & 1) * 16384 + (u) * 4096 + wave * 512)

  STAGE_B(0, 0); STAGE_B(0, 1); STAGE_B(0, 2); STAGE_B(0, 3);
  STAGE_A(0, 0); STAGE_A(0, 1); STAGE_A(0, 2); STAGE_A(0, 3);
  if (NT > 1) {
    STAGE_B(1, 0); STAGE_B(1, 1); STAGE_B(1, 2); STAGE_B(1, 3);
    STAGE_A(1, 0); STAGE_A(1, 1);
    asm volatile("s_waitcnt vmcnt(6)" ::: "memory");
  } else {
    asm volatile("s_waitcnt vmcnt(0)" ::: "memory");
  }
  __builtin_amdgcn_s_barrier();

  for (int kt = 0; kt < NT; ++kt) {
    const u16* Ab = At + (kt & 1) * 16384;
    const u16* Bb = Bts + (kt & 1) * 16384;
    short8 bfr[4][2];
    #pragma unroll
    for (int q = 0; q < 4; ++q) {
      if (q == 0) {
        #pragma unroll
        for (int j = 0; j < 4; ++j)
          #pragma unroll
          for (int s = 0; s < 2; ++s)
            bfr[j][s] = *(const short8*)(Bb + (wn + j * 16 + r16) * 64 +
                                         (((s * 4 + quad) ^ (r16 & 7)) * 8));
      }
      short8 af[2][2];
      #pragma unroll
      for (int di = 0; di < 2; ++di)
        #pragma unroll
        for (int s = 0; s < 2; ++s)
          af[di][s] = *(const short8*)(Ab + (q * 64 + halfw * 32 + di * 16 + r16) * 64 +
                                       (((s * 4 + quad) ^ (r16 & 7)) * 8));
      if (q == 0)      { if (kt + 1 < NT) { STAGE_A(kt + 1, 2); STAGE_A(kt + 1, 3); } }
      else if (q == 1) { if (kt + 2 < NT) { STAGE_B(kt + 2, 0); STAGE_B(kt + 2, 1); } }
      else if (q == 2) { if (kt + 2 < NT) { STAGE_B(kt + 2, 2); STAGE_B(kt + 2, 3); } }
      else             { if (kt + 2 < NT) { STAGE_A(kt + 2, 0); STAGE_A(kt + 2, 1); } }
      __builtin_amdgcn_s_barrier();
      asm volatile("s_waitcnt lgkmcnt(0)" ::: "memory");
      __builtin_amdgcn_s_setprio(1);
      #pragma unroll
      for (int j = 0; j < 4; ++j) {
        acc[2 * q][j]     = MFMA_BF16(af[0][0], bfr[j][0], acc[2 * q][j]);
        acc[2 * q][j]     = MFMA_BF16(af[0][1], bfr[j][1], acc[2 * q][j]);
        acc[2 * q + 1][j] = MFMA_BF16(af[1][0], bfr[j][0], acc[2 * q + 1][j]);
        acc[2 * q + 1][j] = MFMA_BF16(af[1][1], bfr[j][1], acc[2 * q + 1][j]);
      }
      __builtin_amdgcn_s_setprio(0);
      if (q == 3) {
        if (kt + 2 < NT)      { asm volatile("s_waitcnt vmcnt(6)" ::: "memory"); }
        else if (kt + 1 < NT) { asm volatile("s_waitcnt vmcnt(0)" ::: "memory"); }
      }
      __builtin_amdgcn_s_barrier();
    }
  }
#undef STAGE_A
#undef STAGE_B

  #pragma unroll
  for (int i = 0; i < 8; ++i) {
    const int rowb = m0 + halfw * 128 + i * 16 + quad * 4;
    #pragma unroll
    for (int j = 0; j < 4; ++j) {
      const int col = n0 + wn + j * 16 + r16;
      #pragma unroll
      for (int rg = 0; rg < 4; ++rg) {
        float val = acc[i][j][rg];
        const int r = rowb + rg;
        if (MODE == 2) {
          val += bias[col];
          val = fmaxf(val, 0.0f);
          outH[(size_t)r * N + col] = f2bf(val);
        } else {
          outF[(size_t)r * N + col] = val;
        }
      }
    }
  }
}

// ============ bf16 MFMA GEMM, 256x128 tile, phase-pipelined ============
// 512 thr = 8 waves (4M x 2N); per-wave 64x64 output, acc[4][4].
// BK=64, dbuf LDS = 96 KiB.  2 phases/K-tile, 16 MFMA each.
// MODE 0: q/k scatter bf16; V blocks (n0>=2048) transposed via LDS ->
//         coalesced vT[bh][dh][s] stores.  MODE 1: fp32; MODE 3: +bias fp32.
template <int MODE>
__global__ __launch_bounds__(512, 2) void gemm256x128_kernel(
    const u16* __restrict__ A, const u16* __restrict__ Bt,
    const int M, const int N, const int K,
    float* __restrict__ outF, u16* __restrict__ outH, const float* __restrict__ bias,
    u16* __restrict__ qo, u16* __restrict__ ko, u16* __restrict__ vo) {
  extern __shared__ u16 smem[];
  u16* At  = smem;                  // [2][256][64]
  u16* Bts = smem + 2 * 256 * 64;   // [2][128][64]
  const int tid = threadIdx.x;
  const int lane = tid & 63, wave = tid >> 6;
  const int quad = lane >> 4, r16 = lane & 15;
  const int w64 = wave >> 1;            // output row quarter (0..3)
  const int wn = (wave & 1) * 64;       // output col offset in tile
  const int m0 = blockIdx.x * 256, n0 = blockIdx.y * 128;
  const int NT = K >> 6;

  const int rowin = wave * 8 + (lane >> 3);   // 0..63 within 64-row unit
  const int sc = lane & 7;

  const u16* Asrc[4];
  const u16* Bsrc[2];
  #pragma unroll
  for (int u = 0; u < 4; ++u) {
    // logical A row of unit u at this thread's slot
    const int ra = ((u & 1) * 2 + (rowin >> 5)) * 64 + (u >> 1) * 32 + (rowin & 31);
    Asrc[u] = A + (size_t)(m0 + ra) * K + (sc ^ (ra & 7)) * 8;
  }
  #pragma unroll
  for (int u = 0; u < 2; ++u) {
    const int rb = u * 64 + rowin;
    Bsrc[u] = Bt + (size_t)(n0 + rb) * K + (sc ^ (rb & 7)) * 8;
  }

  float4v acc[4][4];
  #pragma unroll
  for (int i = 0; i < 4; ++i)
    #pragma unroll
    for (int j = 0; j < 4; ++j) acc[i][j] = (float4v)0.0f;

#define STAGE_A(t, u) gl2lds16(Asrc[u] + (t) * 64, At  + ((t) & 1) * 16384 + (u) * 4096 + wave * 512)
#define STAGE_B(t, u) gl2lds16(Bsrc[u] + (t) * 64, Bts + ((t) & 1) * 8192 + (u) * 4096 + wave * 512)

  // prologue: tile0 all 6 units; tile1 B0,B1,A0,A1 -> wait tile0 landed
  STAGE_B(0, 0); STAGE_B(0, 1); STAGE_A(0, 0); STAGE_A(0, 1);
  STAGE_A(0, 2); STAGE_A(0, 3);
  STAGE_B(1, 0); STAGE_B(1, 1); STAGE_A(1, 0); STAGE_A(1, 1);
  asm volatile("s_waitcnt vmcnt(6)" ::: "memory");
  __builtin_amdgcn_s_barrier();

  for (int kt = 0; kt < NT; ++kt) {
    const u16* Ab = At + (kt & 1) * 16384;
    const u16* Bb = Bts + (kt & 1) * 8192;
    // ---- phase 0: rows w64*64 + [0,32) ----
    short8 bfr[4][2];
    #pragma unroll
    for (int j = 0; j < 4; ++j)
      #pragma unroll
      for (int s = 0; s < 2; ++s)
        bfr[j][s] = *(const short8*)(Bb + (wn + j * 16 + r16) * 64 +
                                     (((s * 4 + quad) ^ (r16 & 7)) * 8));
    {
      short8 af[2][2];
      #pragma unroll
      for (int di = 0; di < 2; ++di)
        #pragma unroll
        for (int s = 0; s < 2; ++s)
          af[di][s] = *(const short8*)(Ab + (w64 * 32 + di * 16 + r16) * 64 +
                                       (((s * 4 + quad) ^ (r16 & 7)) * 8));
      if (kt + 1 < NT) { STAGE_A(kt + 1, 2); STAGE_A(kt + 1, 3); }
      __builtin_amdgcn_s_barrier();
      asm volatile("s_waitcnt lgkmcnt(0)" ::: "memory");
      __builtin_amdgcn_s_setprio(1);
      #pragma unroll
      for (int j = 0; j < 4; ++j) {
        acc[0][j] = MFMA_BF16(af[0][0], bfr[j][0], acc[0][j]);
        acc[0][j] = MFMA_BF16(af[0][1], bfr[j][1], acc[0][j]);
        acc[1][j] = MFMA_BF16(af[1][0], bfr[j][0], acc[1][j]);
        acc[1][j] = MFMA_BF16(af[1][1], bfr[j][1], acc[1][j]);
      }
      __builtin_amdgcn_s_setprio(0);
      if (kt + 1 < NT) { asm volatile("s_waitcnt vmcnt(6)" ::: "memory"); }
      else             { asm volatile("s_waitcnt vmcnt(0)" ::: "memory"); }
      __builtin_amdgcn_s_barrier();
    }
    // ---- phase 1: rows w64*64 + [32,64) ----
    {
      short8 af[2][2];
      #pragma unroll
      for (int di = 0; di < 2; ++di)
        #pragma unroll
        for (int s = 0; s < 2; ++s)
          af[di][s] = *(const short8*)(Ab + (128 + w64 * 32 + di * 16 + r16) * 64 +
                                       (((s * 4 + quad) ^ (r16 & 7)) * 8));
      if (kt + 2 < NT) {
        STAGE_B(kt + 2, 0); STAGE_B(kt + 2, 1);
        STAGE_A(kt + 2, 0); STAGE_A(kt + 2, 1);
      }
      __builtin_amdgcn_s_barrier();
      asm volatile("s_waitcnt lgkmcnt(0)" ::: "memory");
      __builtin_amdgcn_s_setprio(1);
      #pragma unroll
      for (int j = 0; j < 4; ++j) {
        acc[2][j] = MFMA_BF16(af[0][0], bfr[j][0], acc[2][j]);
        acc[2][j] = MFMA_BF16(af[0][1], bfr[j][1], acc[2][j]);
        acc[3][j] = MFMA_BF16(af[1][0], bfr[j][0], acc[3][j]);
        acc[3][j] = MFMA_BF16(af[1][1], bfr[j][1], acc[3][j]);
      }
      __builtin_amdgcn_s_setprio(0);
      if (kt + 1 < NT) {
        if (kt + 2 < NT) { asm volatile("s_waitcnt vmcnt(6)" ::: "memory"); }
        else             { asm volatile("s_waitcnt vmcnt(2)" ::: "memory"); }
      }
      __builtin_amdgcn_s_barrier();
    }
  }
#undef STAGE_A
#undef STAGE_B

  if (MODE == 0 && n0 >= 2 * D_) {
    // V block: this block covers exactly vT[bh][0..127][s0..s0+255].
    // Stage [dh][s] in LDS (pad 260 u16 -> dh-stride 130 dwords, 2-way max),
    // then coalesced short8 stores (512B runs per dh row).
    u16* vlds = smem;   // 128*260*2 = 66560 B <= 96 KiB
    __syncthreads();
    #pragma unroll
    for (int i = 0; i < 4; ++i) {
      const int sl = w64 * 64 + i * 16 + quad * 4;
      #pragma unroll
      for (int j = 0; j < 4; ++j) {
        const int dh = wn + j * 16 + r16;
        #pragma unroll
        for (int rg = 0; rg < 4; ++rg)
          vlds[dh * 260 + sl + rg] = f2bf(acc[i][j][rg]);
      }
    }
    __syncthreads();
    const int b = m0 >> 11, s0 = m0 & 2047;
    const int h = (n0 - 2 * D_) >> 7;
    u16* vbase = vo + (size_t)(b * H_ + h) * DH_ * S_ + s0;
    #pragma unroll
    for (int p = 0; p < 8; ++p) {
      const int dh = p * 16 + (tid >> 5);
      const int ss = (tid & 31) * 8;
      short8 v8 = *(const short8*)&vlds[dh * 260 + ss];
      *(short8*)(vbase + (size_t)dh * S_ + ss) = v8;
    }
    return;
  }

  // epilogue: D row = quad*4+rg within 16-row frag; col = r16 within 16-col frag
  #pragma unroll
  for (int i = 0; i < 4; ++i) {
    const int rowb = m0 + w64 * 64 + i * 16 + quad * 4;
    #pragma unroll
    for (int j = 0; j < 4; ++j) {
      const int col = n0 + wn + j * 16 + r16;
      #pragma unroll
      for (int rg = 0; rg < 4; ++rg) {
        float val = acc[i][j][rg];
        const int r = rowb + rg;
        if (MODE == 0) {
          const int part = col >> 10, cc = col & 1023;
          const int h = cc >> 7, dh = cc & 127;
          const int b = r >> 11, s = r & 2047;
          if (part == 0) {
            qo[((size_t)(b * H_ + h) * S_ + s) * DH_ + dh] = f2bf(val * CSCALE_);
          } else {
            ko[((size_t)(b * H_ + h) * S_ + s) * DH_ + dh] = f2bf(val);
          }
        } else if (MODE == 1) {
          outF[(size_t)r * N + col] = val;
        } else {
          val += bias[col];
          outF[(size_t)r * N + col] = val;
        }
      }
    }
  }
}

// ---------------- flash causal attention (S^T formulation) ----------------
// Q (pre-scaled), K: [bh][S][DH] bf16; Vt: [bh][DH][S] bf16; O: [rows][D] bf16.
// 512 pair-blocks: id&7 -> XCD (round-robin dispatch), 16 pair-blocks of one
// bh per XCD -> K/V L2-resident (measured FETCH 259->25MB).  Each block runs
// q-tiles {p, 31-p} -> uniform 33 kb-iters.  Async-STAGE (T14) + defer-max
// (T13, THR=8 in log2 domain).
__global__ __launch_bounds__(256) void attn_kernel(
    const u16* __restrict__ Q, const u16* __restrict__ Kg,
    const u16* __restrict__ Vtg, u16* __restrict__ O) {
  __shared__ u16 Ks[64][136];     // [key][d]
  __shared__ u16 Vt[128][72];     // [d][key]
  __shared__ u16 Pw[4][16][72];   // per-wave P [q][key]
  const int tid = threadIdx.x;
  const int lane = tid & 63, wave = tid >> 6;
  const int quad = lane >> 4, r16 = lane & 15;
  const int id = blockIdx.x;                    // 0..511
  const int bh = (id & 7) * 4 + (id >> 7);      // 16 pair-blocks of bh per XCD
  const int pairIdx = (id >> 3) & 15;           // 0..15
  const size_t base = (size_t)bh * S_ * DH_;
  const size_t vtb = (size_t)bh * DH_ * S_;
  const int b = bh >> 3, h = bh & 7;

  // hoisted staging addresses
  const u16* kg0 = Kg + base + (size_t)(tid >> 4) * DH_ + (tid & 15) * 8;
  u16* ksl = &Ks[tid >> 4][(tid & 15) * 8];
  const u16* vg0 = Vtg + vtb + (size_t)(tid >> 3) * S_ + (tid & 7) * 8;
  u16* vtl = &Vt[tid >> 3][(tid & 7) * 8];

  short8 rk[4], rv[4];
#define LOADKV(kb_)                                                        \
  do {                                                                     \
    _Pragma("unroll")                                                      \
    for (int i_ = 0; i_ < 4; ++i_)                                         \
      rk[i_] = *(const short8*)(kg0 + (size_t)((kb_) * 64 + i_ * 16) * DH_); \
    _Pragma("unroll")                                                      \
    for (int i_ = 0; i_ < 4; ++i_)                                         \
      rv[i_] = *(const short8*)(vg0 + (size_t)i_ * 32 * S_ + (kb_) * 64);  \
  } while (0)

  for (int half = 0; half < 2; ++half) {
    const int qb = (half == 0) ? pairIdx : 31 - pairIdx;
    const int qr = qb * 64 + wave * 16 + r16;  // this lane's q-row (as B-col)

    // Q fragment: B-operand layout B[k=quad*8+j][n=r16] == Q[q=r16][k] regs
    short8 aq[4];
    #pragma unroll
    for (int ks = 0; ks < 4; ++ks)
      aq[ks] = *(const short8*)(Q + base + (size_t)qr * DH_ + ks * 32 + quad * 8);

    float4v acco[8];
    #pragma unroll
    for (int i = 0; i < 8; ++i) acco[i] = (float4v)0.0f;
    float m_q = -1e30f, l_q = 0.0f;  // per q=r16, replicated across quads

    LOADKV(0);  // prefetch tile 0 for this half

    for (int kb = 0; kb <= qb; ++kb) {
      __syncthreads();   // prior iter's LDS reads done before overwrite
      // ds_write staged regs (compiler inserts vmcnt wait on rk/rv here)
      #pragma unroll
      for (int i = 0; i < 4; ++i) *(short8*)(ksl + i * 16 * 136) = rk[i];
      #pragma unroll
      for (int i = 0; i < 4; ++i) *(short8*)(vtl + i * 32 * 72) = rv[i];
      __syncthreads();
      if (kb < qb) LOADKV(kb + 1);  // prefetch next; latency hides under compute

      // S^T tile: rows = keys (64), cols = q (16/wave). A = K, B = Qfrag.
      float4v accs[4];
      #pragma unroll
      for (int t = 0; t < 4; ++t) accs[t] = (float4v)0.0f;
      #pragma unroll
      for (int ks = 0; ks < 4; ++ks) {
        #pragma unroll
        for (int t = 0; t < 4; ++t) {
          short8 ak = *(const short8*)&Ks[t * 16 + r16][ks * 32 + quad * 8];
          accs[t] = MFMA_BF16(ak, aq[ks], accs[t]);
        }
      }
      // causal mask on diagonal block; scores already in log2 domain
      if (kb == qb) {
        #pragma unroll
        for (int t = 0; t < 4; ++t)
          #pragma unroll
          for (int rg = 0; rg < 4; ++rg) {
            int kc = kb * 64 + t * 16 + quad * 4 + rg;
            if (kc > qr) accs[t][rg] = -1e30f;
          }
      }
      // online softmax: lane owns q=r16; 16 local scores + 2 shfl (quads)
      float mv = accs[0][0];
      #pragma unroll
      for (int t = 0; t < 4; ++t)
        #pragma unroll
        for (int rg = 0; rg < 4; ++rg) mv = fmaxf(mv, accs[t][rg]);
      mv = fmaxf(mv, __shfl_xor(mv, 16));
      mv = fmaxf(mv, __shfl_xor(mv, 32));
      // defer-max (T13): skip O-rescale when tile max within THR of running
      // max (P bounded by 2^8, fp32-safe). Wave-uniform branch.
      const bool nore = __all(mv <= m_q + 8.0f) != 0;
      const float mnew = nore ? m_q : fmaxf(m_q, mv);
      float alpha = 1.0f;
      if (!nore) alpha = __builtin_amdgcn_exp2f(m_q - mnew);
      float s0 = 0.0f;
      #pragma unroll
      for (int t = 0; t < 4; ++t)
        #pragma unroll
        for (int rg = 0; rg < 4; ++rg) {
          float p = __builtin_amdgcn_exp2f(accs[t][rg] - mnew);
          accs[t][rg] = p;
          s0 += p;
        }
      s0 += __shfl_xor(s0, 16);
      s0 += __shfl_xor(s0, 32);
      l_q = nore ? (l_q + s0) : (l_q * alpha + s0);
      m_q = mnew;

      // P^T (C-layout: 4 consecutive keys/lane) -> Pw[q][key], packed b64
      #pragma unroll
      for (int t = 0; t < 4; ++t) {
        union { float f; unsigned u; } c0, c1, c2, c3;
        c0.f = accs[t][0]; c1.f = accs[t][1]; c2.f = accs[t][2]; c3.f = accs[t][3];
        uint2 pk;
        pk.x = ((c0.u + 0x8000u) >> 16) | ((c1.u + 0x8000u) & 0xffff0000u);
        pk.y = ((c2.u + 0x8000u) >> 16) | ((c3.u + 0x8000u) & 0xffff0000u);
        *(uint2*)&Pw[wave][r16][t * 16 + quad * 4] = pk;
      }
      if (!nore) {
        // rescale O by alpha of its rows q = quad*4+rg
        float al[4];
        #pragma unroll
        for (int rg = 0; rg < 4; ++rg) al[rg] = __shfl(alpha, quad * 4 + rg);
        #pragma unroll
        for (int nt = 0; nt < 8; ++nt)
          #pragma unroll
          for (int rg = 0; rg < 4; ++rg) acco[nt][rg] *= al[rg];
      }
      asm volatile("s_waitcnt lgkmcnt(0)" ::: "memory");
      // O += P @ V
      #pragma unroll
      for (int ks2 = 0; ks2 < 2; ++ks2) {
        short8 ap = *(const short8*)&Pw[wave][r16][ks2 * 32 + quad * 8];
        #pragma unroll
        for (int nt = 0; nt < 8; ++nt) {
          short8 bv = *(const short8*)&Vt[nt * 16 + r16][ks2 * 32 + quad * 8];
          acco[nt] = MFMA_BF16(ap, bv, acco[nt]);
        }
      }
    }

    // epilogue: O rows q=quad*4+rg, cols d=nt*16+r16
    float lr[4];
    #pragma unroll
    for (int rg = 0; rg < 4; ++rg) lr[rg] = __shfl(l_q, quad * 4 + rg);
    const int sbase = qb * 64 + wave * 16 + quad * 4;
    #pragma unroll
    for (int nt = 0; nt < 8; ++nt)
      #pragma unroll
      for (int rg = 0; rg < 4; ++rg) {
        float val = acco[nt][rg] / lr[rg];
        O[((size_t)(b * S_ + sbase + rg)) * D_ + h * DH_ + nt * 16 + r16] = f2bf(val);
      }
  }
#undef LOADKV
}

// ---------- layernorm: y = LN(a + res) * g + be ----------
__global__ __launch_bounds__(256) void ln_kernel(
    const float* __restrict__ a, const float* __restrict__ res,
    const float* __restrict__ g, const float* __restrict__ be,
    float* __restrict__ xf, u16* __restrict__ xb) {
  __shared__ float red[8];
  const int row = blockIdx.x, tid = threadIdx.x;
  const float4 va = ((const float4*)(a + (size_t)row * D_))[tid];
  const float4 vr = ((const float4*)(res + (size_t)row * D_))[tid];
  float4 v;
  v.x = va.x + vr.x; v.y = va.y + vr.y; v.z = va.z + vr.z; v.w = va.w + vr.w;
  float s = v.x + v.y + v.z + v.w;
  float q = v.x * v.x + v.y * v.y + v.z * v.z + v.w * v.w;
  #pragma unroll
  for (int m = 1; m < 64; m <<= 1) {
    s += __shfl_xor(s, m);
    q += __shfl_xor(q, m);
  }
  const int wave = tid >> 6, lane = tid & 63;
  if (lane == 0) { red[wave] = s; red[4 + wave] = q; }
  __syncthreads();
  s = red[0] + red[1] + red[2] + red[3];
  q = red[4] + red[5] + red[6] + red[7];
  const float mu = s * (1.0f / D_);
  const float var = q * (1.0f / D_) - mu * mu;
  const float inv = rsqrtf(var + EPS_);
  const float4 gg = ((const float4*)g)[tid];
  const float4 bb = ((const float4*)be)[tid];
  float4 y;
  y.x = (v.x - mu) * inv * gg.x + bb.x;
  y.y = (v.y - mu) * inv * gg.y + bb.y;
  y.z = (v.z - mu) * inv * gg.z + bb.z;
  y.w = (v.w - mu) * inv * gg.w + bb.w;
  ((float4*)(xf + (size_t)row * D_))[tid] = y;
  if (xb) {
    ushort4 u;
    u.x = f2bf(y.x); u.y = f2bf(y.y); u.z = f2bf(y.z); u.w = f2bf(y.w);
    ((ushort4*)(xb + (size_t)row * D_))[tid] = u;
  }
}

extern "C" void kernel_launch(void* const* d_in, const int* in_sizes, int n_in,
                              void* d_out, int out_size, void* d_ws, size_t ws_size,
                              hipStream_t stream) {
  const float* src   = (const float*)d_in[0];
  const float* w_qkv = (const float*)d_in[1];
  const float* w_out = (const float*)d_in[2];
  const float* w1    = (const float*)d_in[3];
  const float* b1    = (const float*)d_in[4];
  const float* w2    = (const float*)d_in[5];
  const float* b2    = (const float*)d_in[6];
  const float* g1    = (const float*)d_in[7];
  const float* be1   = (const float*)d_in[8];
  const float* g2    = (const float*)d_in[9];
  const float* be2   = (const float*)d_in[10];
  float* out = (float*)d_out;

  char* ws = (char*)d_ws;
  size_t off = 0;
  auto alloc = [&](size_t bytes) -> void* {
    void* p = ws + off;
    off += (bytes + 255) & ~(size_t)255;
    return p;
  };
  u16* src_bf = (u16*)alloc((size_t)ROWS_ * D_ * 2);
  u16* wqkvT  = (u16*)alloc((size_t)3 * D_ * D_ * 2);   // [3072][1024]
  u16* woutT  = (u16*)alloc((size_t)D_ * D_ * 2);
  u16* w1T    = (u16*)alloc((size_t)DFF_ * D_ * 2);     // [4096][1024]
  u16* w2T    = (u16*)alloc((size_t)D_ * DFF_ * 2);     // [1024][4096]
  u16* qbuf   = (u16*)alloc((size_t)ROWS_ * D_ * 2);
  u16* kbuf   = (u16*)alloc((size_t)ROWS_ * D_ * 2);
  u16* vT     = (u16*)alloc((size_t)ROWS_ * D_ * 2);    // V written transposed
  u16* obuf   = (u16*)alloc((size_t)ROWS_ * D_ * 2);
  float* proj = (float*)alloc((size_t)ROWS_ * D_ * 4);
  float* xf   = (float*)alloc((size_t)ROWS_ * D_ * 4);
  u16* xb     = (u16*)alloc((size_t)ROWS_ * D_ * 2);
  u16* h1     = qbuf;   // alias: q,k,o dead before FFN1 writes
  float* ff   = proj;   // alias: proj dead after LN1

  const int GSMEM  = 131072;  // 256x256: 2 bufs x (A 32KB + B 32KB)
  const int GSMEM2 = 98304;   // 256x128: 2 bufs x (A 32KB + B 16KB)
  hipFuncSetAttribute((const void*)gemm256_kernel<2>, hipFuncAttributeMaxDynamicSharedMemorySize, GSMEM);
  hipFuncSetAttribute((const void*)gemm256x128_kernel<0>, hipFuncAttributeMaxDynamicSharedMemorySize, GSMEM2);
  hipFuncSetAttribute((const void*)gemm256x128_kernel<1>, hipFuncAttributeMaxDynamicSharedMemorySize, GSMEM2);
  hipFuncSetAttribute((const void*)gemm256x128_kernel<3>, hipFuncAttributeMaxDynamicSharedMemorySize, GSMEM2);

  cast_bf16_kernel<<<2048, 256, 0, stream>>>(src, src_bf, ROWS_ * D_ / 4);
  transpose_cast_kernel<<<dim3(D_ / 32, 3 * D_ / 32), 256, 0, stream>>>(w_qkv, wqkvT, D_, 3 * D_);
  transpose_cast_kernel<<<dim3(D_ / 32, D_ / 32), 256, 0, stream>>>(w_out, woutT, D_, D_);
  transpose_cast_kernel<<<dim3(D_ / 32, DFF_ / 32), 256, 0, stream>>>(w1, w1T, D_, DFF_);
  transpose_cast_kernel<<<dim3(DFF_ / 32, D_ / 32), 256, 0, stream>>>(w2, w2T, DFF_, D_);

  // QKV: N=3072 -> 32x24 = 768 blocks; V blocks stored transposed (LDS-coalesced)
  gemm256x128_kernel<0><<<dim3(ROWS_ / 256, 3 * D_ / 128), 512, GSMEM2, stream>>>(
      src_bf, wqkvT, ROWS_, 3 * D_, D_, nullptr, nullptr, nullptr, qbuf, kbuf, vT);
  // attn: 512 pair-blocks, XCD-grouped (proven grid) + defer-max
  attn_kernel<<<512, 256, 0, stream>>>(qbuf, kbuf, vT, obuf);
  // out-proj: N=1024 -> 32x8 = 256 blocks
  gemm256x128_kernel<1><<<dim3(ROWS_ / 256, D_ / 128), 512, GSMEM2, stream>>>(
      obuf, woutT, ROWS_, D_, D_, proj, nullptr, nullptr, nullptr, nullptr, nullptr);
  ln_kernel<<<ROWS_, 256, 0, stream>>>(proj, src, g1, be1, xf, xb);
  // FFN1: N=4096 -> 256x256 tile: 32x16 = 512 blocks
  gemm256_kernel<2><<<dim3(ROWS_ / 256, DFF_ / 256), 512, GSMEM, stream>>>(
      xb, w1T, ROWS_, DFF_, D_, nullptr, h1, b1, nullptr, nullptr, nullptr);
  // FFN2: N=1024, K=4096 -> 32x8 = 256 blocks
  gemm256x128_kernel<3><<<dim3(ROWS_ / 256, D_ / 128), 512, GSMEM2, stream>>>(
      h1, w2T, ROWS_, D_, DFF_, ff, nullptr, b2, nullptr, nullptr, nullptr);
  ln_kernel<<<ROWS_, 256, 0, stream>>>(ff, xf, g2, be2, out, nullptr);
}

// Round 9
// 474.741 us; speedup vs baseline: 1.0768x; 1.0121x over previous
//
#include <hip/hip_runtime.h>

typedef unsigned short u16;
typedef __attribute__((ext_vector_type(8))) short short8;
typedef __attribute__((ext_vector_type(4))) float float4v;

#define MFMA_BF16(a, b, c) __builtin_amdgcn_mfma_f32_16x16x32_bf16((a), (b), (c), 0, 0, 0)

#define B_ 4
#define S_ 2048
#define D_ 1024
#define H_ 8
#define DH_ 128
#define DFF_ 4096
#define EPS_ 1e-5f
#define ROWS_ (B_ * S_)   // 8192
#define CSCALE_ 0.12751672939502f  // (1/sqrt(128)) * log2(e), folded into Q

__device__ __forceinline__ u16 f2bf(float f) {
  union { float f; unsigned u; } x; x.f = f;
  unsigned r = x.u + 0x7fffu + ((x.u >> 16) & 1u);
  return (u16)(r >> 16);
}

typedef __attribute__((address_space(1))) const unsigned int guint;
typedef __attribute__((address_space(3))) unsigned int luint;
__device__ __forceinline__ void gl2lds16(const u16* g, u16* l) {
  // each lane: 16B from its own g -> wave-uniform lds base + lane*16
  __builtin_amdgcn_global_load_lds((guint*)g, (luint*)l, 16, 0, 0);
}

// ---------------- cast fp32 -> bf16 (layout preserved) ----------------
__global__ void cast_bf16_kernel(const float* __restrict__ in, u16* __restrict__ out, int n4) {
  int i = blockIdx.x * blockDim.x + threadIdx.x;
  int stride = gridDim.x * blockDim.x;
  for (; i < n4; i += stride) {
    float4 v = ((const float4*)in)[i];
    ushort4 u;
    u.x = f2bf(v.x); u.y = f2bf(v.y); u.z = f2bf(v.z); u.w = f2bf(v.w);
    ((ushort4*)out)[i] = u;
  }
}

// ---------- cast+transpose fp32 [K][N] -> bf16 [N][K] (weights) ----------
__global__ void transpose_cast_kernel(const float* __restrict__ in, u16* __restrict__ out,
                                      int K, int N) {
  __shared__ float t[32][33];
  int k0 = blockIdx.x * 32, n0 = blockIdx.y * 32;
  int tx = threadIdx.x & 31, ty = threadIdx.x >> 5;  // 32x8 threads
  #pragma unroll
  for (int i = 0; i < 4; ++i)
    t[ty + 8 * i][tx] = in[(size_t)(k0 + ty + 8 * i) * N + n0 + tx];
  __syncthreads();
  #pragma unroll
  for (int i = 0; i < 4; ++i)
    out[(size_t)(n0 + ty + 8 * i) * K + k0 + tx] = f2bf(t[tx][ty + 8 * i]);
}

// ============== bf16 MFMA GEMM, 256x256 tile, 8-phase schedule ==============
// C[M,N] = A[M,K] @ Bt[N,K]^T.  512 thr = 8 waves (2M x 4N); per-wave 128x64.
// lda = row stride (elements) of A and Bt.
// MODE 2: +bias, relu, bf16 out.
// MODE 5: split-K over blockIdx.z (z*K col offset); z=0 -> outF (+bias),
//         z=1 -> outF2 raw partial.
template <int MODE>
__global__ __launch_bounds__(512, 2) void gemm256_kernel(
    const u16* __restrict__ A, const u16* __restrict__ Bt,
    const int M, const int N, const int K, const int lda,
    float* __restrict__ outF, float* __restrict__ outF2,
    u16* __restrict__ outH, const float* __restrict__ bias,
    u16* __restrict__ qo, u16* __restrict__ ko, u16* __restrict__ vo) {
  extern __shared__ u16 smem[];
  u16* At  = smem;                  // [2][256][64] permuted rows, swizzled chunks
  u16* Bts = smem + 2 * 256 * 64;   // [2][256][64] linear rows, swizzled chunks
  const int tid = threadIdx.x;
  const int lane = tid & 63, wave = tid >> 6;
  const int quad = lane >> 4, r16 = lane & 15;
  const int halfw = wave >> 2;          // output row half (0/1)
  const int wn = (wave & 3) * 64;       // output col offset in tile
  const int m0 = blockIdx.x * 256, n0 = blockIdx.y * 256;
  const int NT = K >> 6;
  const int kof = (MODE == 5) ? (int)blockIdx.z * K : 0;

  const int rowin = wave * 8 + (lane >> 3);   // 0..63 within unit
  const int sc = lane & 7;
  const int shalf = rowin >> 5, srr = rowin & 31;

  const u16* Asrc[4];
  const u16* Bsrc[4];
  #pragma unroll
  for (int u = 0; u < 4; ++u) {
    const int ra = shalf * 128 + u * 32 + srr;   // logical A row of unit u
    Asrc[u] = A + (size_t)(m0 + ra) * lda + kof + (sc ^ (ra & 7)) * 8;
    const int rb = u * 64 + rowin;               // logical B row of unit u
    Bsrc[u] = Bt + (size_t)(n0 + rb) * lda + kof + (sc ^ (rb & 7)) * 8;
  }

  float4v acc[8][4];
  #pragma unroll
  for (int i = 0; i < 8; ++i)
    #pragma unroll
    for (int j = 0; j < 4; ++j) acc[i][j] = (float4v)0.0f;

#define STAGE_A(t, u) gl2lds16(Asrc[u] + (t) * 64, At  + ((t) & 1) * 16384 + (u) * 4096 + wave * 512)
#define STAGE_B(t, u) gl2lds16(Bsrc[u] + (t) * 64, Bts + ((t) & 1) * 16384 + (u) * 4096 + wave * 512)

  STAGE_B(0, 0); STAGE_B(0, 1); STAGE_B(0, 2); STAGE_B(0, 3);
  STAGE_A(0, 0); STAGE_A(0, 1); STAGE_A(0, 2); STAGE_A(0, 3);
  if (NT > 1) {
    STAGE_B(1, 0); STAGE_B(1, 1); STAGE_B(1, 2); STAGE_B(1, 3);
    STAGE_A(1, 0); STAGE_A(1, 1);
    asm volatile("s_waitcnt vmcnt(6)" ::: "memory");
  } else {
    asm volatile("s_waitcnt vmcnt(0)" ::: "memory");
  }
  __builtin_amdgcn_s_barrier();

  for (int kt = 0; kt < NT; ++kt) {
    const u16* Ab = At + (kt & 1) * 16384;
    const u16* Bb = Bts + (kt & 1) * 16384;
    short8 bfr[4][2];
    #pragma unroll
    for (int q = 0; q < 4; ++q) {
      if (q == 0) {
        #pragma unroll
        for (int j = 0; j < 4; ++j)
          #pragma unroll
          for (int s = 0; s < 2; ++s)
            bfr[j][s] = *(const short8*)(Bb + (wn + j * 16 + r16) * 64 +
                                         (((s * 4 + quad) ^ (r16 & 7)) * 8));
      }
      short8 af[2][2];
      #pragma unroll
      for (int di = 0; di < 2; ++di)
        #pragma unroll
        for (int s = 0; s < 2; ++s)
          af[di][s] = *(const short8*)(Ab + (q * 64 + halfw * 32 + di * 16 + r16) * 64 +
                                       (((s * 4 + quad) ^ (r16 & 7)) * 8));
      if (q == 0)      { if (kt + 1 < NT) { STAGE_A(kt + 1, 2); STAGE_A(kt + 1, 3); } }
      else if (q == 1) { if (kt + 2 < NT) { STAGE_B(kt + 2, 0); STAGE_B(kt + 2, 1); } }
      else if (q == 2) { if (kt + 2 < NT) { STAGE_B(kt + 2, 2); STAGE_B(kt + 2, 3); } }
      else             { if (kt + 2 < NT) { STAGE_A(kt + 2, 0); STAGE_A(kt + 2, 1); } }
      __builtin_amdgcn_s_barrier();
      asm volatile("s_waitcnt lgkmcnt(0)" ::: "memory");
      __builtin_amdgcn_s_setprio(1);
      #pragma unroll
      for (int j = 0; j < 4; ++j) {
        acc[2 * q][j]     = MFMA_BF16(af[0][0], bfr[j][0], acc[2 * q][j]);
        acc[2 * q][j]     = MFMA_BF16(af[0][1], bfr[j][1], acc[2 * q][j]);
        acc[2 * q + 1][j] = MFMA_BF16(af[1][0], bfr[j][0], acc[2 * q + 1][j]);
        acc[2 * q + 1][j] = MFMA_BF16(af[1][1], bfr[j][1], acc[2 * q + 1][j]);
      }
      __builtin_amdgcn_s_setprio(0);
      if (q == 3) {
        if (kt + 2 < NT)      { asm volatile("s_waitcnt vmcnt(6)" ::: "memory"); }
        else if (kt + 1 < NT) { asm volatile("s_waitcnt vmcnt(0)" ::: "memory"); }
      }
      __builtin_amdgcn_s_barrier();
    }
  }
#undef STAGE_A
#undef STAGE_B

  #pragma unroll
  for (int i = 0; i < 8; ++i) {
    const int rowb = m0 + halfw * 128 + i * 16 + quad * 4;
    #pragma unroll
    for (int j = 0; j < 4; ++j) {
      const int col = n0 + wn + j * 16 + r16;
      #pragma unroll
      for (int rg = 0; rg < 4; ++rg) {
        float val = acc[i][j][rg];
        const int r = rowb + rg;
        if (MODE == 2) {
          val += bias[col];
          val = fmaxf(val, 0.0f);
          outH[(size_t)r * N + col] = f2bf(val);
        } else if (MODE == 5) {
          float* dst = blockIdx.z ? outF2 : outF;
          if (blockIdx.z == 0) val += bias[col];
          dst[(size_t)r * N + col] = val;
        } else {
          outF[(size_t)r * N + col] = val;
        }
      }
    }
  }
}

// ============ bf16 MFMA GEMM, 256x128 tile, phase-pipelined ============
// 512 thr = 8 waves (4M x 2N); per-wave 64x64 output, acc[4][4].
// MODE 0: q/k scatter bf16; V blocks (n0>=2048) transposed via LDS ->
//         coalesced vT[bh][dh][s] stores.  MODE 1: fp32; MODE 3: +bias fp32.
template <int MODE>
__global__ __launch_bounds__(512, 2) void gemm256x128_kernel(
    const u16* __restrict__ A, const u16* __restrict__ Bt,
    const int M, const int N, const int K,
    float* __restrict__ outF, u16* __restrict__ outH, const float* __restrict__ bias,
    u16* __restrict__ qo, u16* __restrict__ ko, u16* __restrict__ vo) {
  extern __shared__ u16 smem[];
  u16* At  = smem;                  // [2][256][64]
  u16* Bts = smem + 2 * 256 * 64;   // [2][128][64]
  const int tid = threadIdx.x;
  const int lane = tid & 63, wave = tid >> 6;
  const int quad = lane >> 4, r16 = lane & 15;
  const int w64 = wave >> 1;            // output row quarter (0..3)
  const int wn = (wave & 1) * 64;       // output col offset in tile
  const int m0 = blockIdx.x * 256, n0 = blockIdx.y * 128;
  const int NT = K >> 6;

  const int rowin = wave * 8 + (lane >> 3);   // 0..63 within 64-row unit
  const int sc = lane & 7;

  const u16* Asrc[4];
  const u16* Bsrc[2];
  #pragma unroll
  for (int u = 0; u < 4; ++u) {
    const int ra = ((u & 1) * 2 + (rowin >> 5)) * 64 + (u >> 1) * 32 + (rowin & 31);
    Asrc[u] = A + (size_t)(m0 + ra) * K + (sc ^ (ra & 7)) * 8;
  }
  #pragma unroll
  for (int u = 0; u < 2; ++u) {
    const int rb = u * 64 + rowin;
    Bsrc[u] = Bt + (size_t)(n0 + rb) * K + (sc ^ (rb & 7)) * 8;
  }

  float4v acc[4][4];
  #pragma unroll
  for (int i = 0; i < 4; ++i)
    #pragma unroll
    for (int j = 0; j < 4; ++j) acc[i][j] = (float4v)0.0f;

#define STAGE_A(t, u) gl2lds16(Asrc[u] + (t) * 64, At  + ((t) & 1) * 16384 + (u) * 4096 + wave * 512)
#define STAGE_B(t, u) gl2lds16(Bsrc[u] + (t) * 64, Bts + ((t) & 1) * 8192 + (u) * 4096 + wave * 512)

  STAGE_B(0, 0); STAGE_B(0, 1); STAGE_A(0, 0); STAGE_A(0, 1);
  STAGE_A(0, 2); STAGE_A(0, 3);
  STAGE_B(1, 0); STAGE_B(1, 1); STAGE_A(1, 0); STAGE_A(1, 1);
  asm volatile("s_waitcnt vmcnt(6)" ::: "memory");
  __builtin_amdgcn_s_barrier();

  for (int kt = 0; kt < NT; ++kt) {
    const u16* Ab = At + (kt & 1) * 16384;
    const u16* Bb = Bts + (kt & 1) * 8192;
    short8 bfr[4][2];
    #pragma unroll
    for (int j = 0; j < 4; ++j)
      #pragma unroll
      for (int s = 0; s < 2; ++s)
        bfr[j][s] = *(const short8*)(Bb + (wn + j * 16 + r16) * 64 +
                                     (((s * 4 + quad) ^ (r16 & 7)) * 8));
    {
      short8 af[2][2];
      #pragma unroll
      for (int di = 0; di < 2; ++di)
        #pragma unroll
        for (int s = 0; s < 2; ++s)
          af[di][s] = *(const short8*)(Ab + (w64 * 32 + di * 16 + r16) * 64 +
                                       (((s * 4 + quad) ^ (r16 & 7)) * 8));
      if (kt + 1 < NT) { STAGE_A(kt + 1, 2); STAGE_A(kt + 1, 3); }
      __builtin_amdgcn_s_barrier();
      asm volatile("s_waitcnt lgkmcnt(0)" ::: "memory");
      __builtin_amdgcn_s_setprio(1);
      #pragma unroll
      for (int j = 0; j < 4; ++j) {
        acc[0][j] = MFMA_BF16(af[0][0], bfr[j][0], acc[0][j]);
        acc[0][j] = MFMA_BF16(af[0][1], bfr[j][1], acc[0][j]);
        acc[1][j] = MFMA_BF16(af[1][0], bfr[j][0], acc[1][j]);
        acc[1][j] = MFMA_BF16(af[1][1], bfr[j][1], acc[1][j]);
      }
      __builtin_amdgcn_s_setprio(0);
      if (kt + 1 < NT) { asm volatile("s_waitcnt vmcnt(6)" ::: "memory"); }
      else             { asm volatile("s_waitcnt vmcnt(0)" ::: "memory"); }
      __builtin_amdgcn_s_barrier();
    }
    {
      short8 af[2][2];
      #pragma unroll
      for (int di = 0; di < 2; ++di)
        #pragma unroll
        for (int s = 0; s < 2; ++s)
          af[di][s] = *(const short8*)(Ab + (128 + w64 * 32 + di * 16 + r16) * 64 +
                                       (((s * 4 + quad) ^ (r16 & 7)) * 8));
      if (kt + 2 < NT) {
        STAGE_B(kt + 2, 0); STAGE_B(kt + 2, 1);
        STAGE_A(kt + 2, 0); STAGE_A(kt + 2, 1);
      }
      __builtin_amdgcn_s_barrier();
      asm volatile("s_waitcnt lgkmcnt(0)" ::: "memory");
      __builtin_amdgcn_s_setprio(1);
      #pragma unroll
      for (int j = 0; j < 4; ++j) {
        acc[2][j] = MFMA_BF16(af[0][0], bfr[j][0], acc[2][j]);
        acc[2][j] = MFMA_BF16(af[0][1], bfr[j][1], acc[2][j]);
        acc[3][j] = MFMA_BF16(af[1][0], bfr[j][0], acc[3][j]);
        acc[3][j] = MFMA_BF16(af[1][1], bfr[j][1], acc[3][j]);
      }
      __builtin_amdgcn_s_setprio(0);
      if (kt + 1 < NT) {
        if (kt + 2 < NT) { asm volatile("s_waitcnt vmcnt(6)" ::: "memory"); }
        else             { asm volatile("s_waitcnt vmcnt(2)" ::: "memory"); }
      }
      __builtin_amdgcn_s_barrier();
    }
  }
#undef STAGE_A
#undef STAGE_B

  if (MODE == 0 && n0 >= 2 * D_) {
    // V block: covers exactly vT[bh][0..127][s0..s0+255]. Stage [dh][s] in
    // LDS (pad 260), then coalesced short8 stores (512B runs per dh row).
    u16* vlds = smem;   // 128*260*2 = 66560 B <= 96 KiB
    __syncthreads();
    #pragma unroll
    for (int i = 0; i < 4; ++i) {
      const int sl = w64 * 64 + i * 16 + quad * 4;
      #pragma unroll
      for (int j = 0; j < 4; ++j) {
        const int dh = wn + j * 16 + r16;
        #pragma unroll
        for (int rg = 0; rg < 4; ++rg)
          vlds[dh * 260 + sl + rg] = f2bf(acc[i][j][rg]);
      }
    }
    __syncthreads();
    const int b = m0 >> 11, s0 = m0 & 2047;
    const int h = (n0 - 2 * D_) >> 7;
    u16* vbase = vo + (size_t)(b * H_ + h) * DH_ * S_ + s0;
    #pragma unroll
    for (int p = 0; p < 8; ++p) {
      const int dh = p * 16 + (tid >> 5);
      const int ss = (tid & 31) * 8;
      short8 v8 = *(const short8*)&vlds[dh * 260 + ss];
      *(short8*)(vbase + (size_t)dh * S_ + ss) = v8;
    }
    return;
  }

  #pragma unroll
  for (int i = 0; i < 4; ++i) {
    const int rowb = m0 + w64 * 64 + i * 16 + quad * 4;
    #pragma unroll
    for (int j = 0; j < 4; ++j) {
      const int col = n0 + wn + j * 16 + r16;
      #pragma unroll
      for (int rg = 0; rg < 4; ++rg) {
        float val = acc[i][j][rg];
        const int r = rowb + rg;
        if (MODE == 0) {
          const int part = col >> 10, cc = col & 1023;
          const int h = cc >> 7, dh = cc & 127;
          const int b = r >> 11, s = r & 2047;
          if (part == 0) {
            qo[((size_t)(b * H_ + h) * S_ + s) * DH_ + dh] = f2bf(val * CSCALE_);
          } else {
            ko[((size_t)(b * H_ + h) * S_ + s) * DH_ + dh] = f2bf(val);
          }
        } else if (MODE == 1) {
          outF[(size_t)r * N + col] = val;
        } else {
          val += bias[col];
          outF[(size_t)r * N + col] = val;
        }
      }
    }
  }
}

// ---------------- flash causal attention (S^T formulation) ----------------
// 512 pair-blocks, XCD-grouped (proven: FETCH 259->25MB).  Async-STAGE (T14)
// + defer-max (T13).  T2 XOR-swizzle on Ks/Vt/Pw: unpadded rows, 16B-chunk
// index c ^= (row&7) on write AND read -> ds_read_b128 2-way max (free).
__global__ __launch_bounds__(256) void attn_kernel(
    const u16* __restrict__ Q, const u16* __restrict__ Kg,
    const u16* __restrict__ Vtg, u16* __restrict__ O) {
  __shared__ u16 Ks[64][128];     // [key][d]    swizzled
  __shared__ u16 Vt[128][64];     // [d][key]    swizzled
  __shared__ u16 Pw[4][16][64];   // per-wave P  swizzled
  const int tid = threadIdx.x;
  const int lane = tid & 63, wave = tid >> 6;
  const int quad = lane >> 4, r16 = lane & 15;
  const int id = blockIdx.x;                    // 0..511
  const int bh = (id & 7) * 4 + (id >> 7);      // 16 pair-blocks of bh per XCD
  const int pairIdx = (id >> 3) & 15;           // 0..15
  const size_t base = (size_t)bh * S_ * DH_;
  const size_t vtb = (size_t)bh * DH_ * S_;
  const int b = bh >> 3, h = bh & 7;

  // staging addresses (swizzled chunk: (chunk ^ (row&7)); row&7 invariant
  // across the i-loop since row steps are multiples of 8)
  const u16* kg0 = Kg + base + (size_t)(tid >> 4) * DH_ + (tid & 15) * 8;
  u16* ksl = &Ks[tid >> 4][((tid & 15) ^ ((tid >> 4) & 7)) * 8];
  const u16* vg0 = Vtg + vtb + (size_t)(tid >> 3) * S_ + (tid & 7) * 8;
  u16* vtl = &Vt[tid >> 3][((tid & 7) ^ ((tid >> 3) & 7)) * 8];

  short8 rk[4], rv[4];
#define LOADKV(kb_)                                                        \
  do {                                                                     \
    _Pragma("unroll")                                                      \
    for (int i_ = 0; i_ < 4; ++i_)                                         \
      rk[i_] = *(const short8*)(kg0 + (size_t)((kb_) * 64 + i_ * 16) * DH_); \
    _Pragma("unroll")                                                      \
    for (int i_ = 0; i_ < 4; ++i_)                                         \
      rv[i_] = *(const short8*)(vg0 + (size_t)i_ * 32 * S_ + (kb_) * 64);  \
  } while (0)

  for (int half = 0; half < 2; ++half) {
    const int qb = (half == 0) ? pairIdx : 31 - pairIdx;
    const int qr = qb * 64 + wave * 16 + r16;  // this lane's q-row (as B-col)

    short8 aq[4];
    #pragma unroll
    for (int ks = 0; ks < 4; ++ks)
      aq[ks] = *(const short8*)(Q + base + (size_t)qr * DH_ + ks * 32 + quad * 8);

    float4v acco[8];
    #pragma unroll
    for (int i = 0; i < 8; ++i) acco[i] = (float4v)0.0f;
    float m_q = -1e30f, l_q = 0.0f;  // per q=r16, replicated across quads

    LOADKV(0);  // prefetch tile 0 for this half

    for (int kb = 0; kb <= qb; ++kb) {
      __syncthreads();   // prior iter's LDS reads done before overwrite
      #pragma unroll
      for (int i = 0; i < 4; ++i) *(short8*)(ksl + i * 16 * 128) = rk[i];
      #pragma unroll
      for (int i = 0; i < 4; ++i) *(short8*)(vtl + i * 32 * 64) = rv[i];
      __syncthreads();
      if (kb < qb) LOADKV(kb + 1);  // prefetch next; latency hides under compute

      // S^T tile: rows = keys (64), cols = q (16/wave). A = K, B = Qfrag.
      float4v accs[4];
      #pragma unroll
      for (int t = 0; t < 4; ++t) accs[t] = (float4v)0.0f;
      #pragma unroll
      for (int ks = 0; ks < 4; ++ks) {
        #pragma unroll
        for (int t = 0; t < 4; ++t) {
          short8 ak = *(const short8*)&Ks[t * 16 + r16][((ks * 4 + quad) ^ (r16 & 7)) * 8];
          accs[t] = MFMA_BF16(ak, aq[ks], accs[t]);
        }
      }
      if (kb == qb) {
        #pragma unroll
        for (int t = 0; t < 4; ++t)
          #pragma unroll
          for (int rg = 0; rg < 4; ++rg) {
            int kc = kb * 64 + t * 16 + quad * 4 + rg;
            if (kc > qr) accs[t][rg] = -1e30f;
          }
      }
      // online softmax: lane owns q=r16; 16 local scores + 2 shfl (quads)
      float mv = accs[0][0];
      #pragma unroll
      for (int t = 0; t < 4; ++t)
        #pragma unroll
        for (int rg = 0; rg < 4; ++rg) mv = fmaxf(mv, accs[t][rg]);
      mv = fmaxf(mv, __shfl_xor(mv, 16));
      mv = fmaxf(mv, __shfl_xor(mv, 32));
      // defer-max (T13): skip O-rescale when tile max within THR of running
      // max (P bounded by 2^8, fp32-safe). Wave-uniform branch.
      const bool nore = __all(mv <= m_q + 8.0f) != 0;
      const float mnew = nore ? m_q : fmaxf(m_q, mv);
      float alpha = 1.0f;
      if (!nore) alpha = __builtin_amdgcn_exp2f(m_q - mnew);
      float s0 = 0.0f;
      #pragma unroll
      for (int t = 0; t < 4; ++t)
        #pragma unroll
        for (int rg = 0; rg < 4; ++rg) {
          float p = __builtin_amdgcn_exp2f(accs[t][rg] - mnew);
          accs[t][rg] = p;
          s0 += p;
        }
      s0 += __shfl_xor(s0, 16);
      s0 += __shfl_xor(s0, 32);
      l_q = nore ? (l_q + s0) : (l_q * alpha + s0);
      m_q = mnew;

      // P^T -> Pw[q][key] packed b64; swizzled 16B chunk = (2t+(quad>>1))^(r16&7),
      // 8B half = quad&1
      #pragma unroll
      for (int t = 0; t < 4; ++t) {
        union { float f; unsigned u; } c0, c1, c2, c3;
        c0.f = accs[t][0]; c1.f = accs[t][1]; c2.f = accs[t][2]; c3.f = accs[t][3];
        uint2 pk;
        pk.x = ((c0.u + 0x8000u) >> 16) | ((c1.u + 0x8000u) & 0xffff0000u);
        pk.y = ((c2.u + 0x8000u) >> 16) | ((c3.u + 0x8000u) & 0xffff0000u);
        *(uint2*)&Pw[wave][r16][(((t * 2 + (quad >> 1)) ^ (r16 & 7)) * 8) + (quad & 1) * 4] = pk;
      }
      if (!nore) {
        float al[4];
        #pragma unroll
        for (int rg = 0; rg < 4; ++rg) al[rg] = __shfl(alpha, quad * 4 + rg);
        #pragma unroll
        for (int nt = 0; nt < 8; ++nt)
          #pragma unroll
          for (int rg = 0; rg < 4; ++rg) acco[nt][rg] *= al[rg];
      }
      asm volatile("s_waitcnt lgkmcnt(0)" ::: "memory");
      // O += P @ V
      #pragma unroll
      for (int ks2 = 0; ks2 < 2; ++ks2) {
        short8 ap = *(const short8*)&Pw[wave][r16][((ks2 * 4 + quad) ^ (r16 & 7)) * 8];
        #pragma unroll
        for (int nt = 0; nt < 8; ++nt) {
          short8 bv = *(const short8*)&Vt[nt * 16 + r16][((ks2 * 4 + quad) ^ (r16 & 7)) * 8];
          acco[nt] = MFMA_BF16(ap, bv, acco[nt]);
        }
      }
    }

    // epilogue: O rows q=quad*4+rg, cols d=nt*16+r16
    float lr[4];
    #pragma unroll
    for (int rg = 0; rg < 4; ++rg) lr[rg] = __shfl(l_q, quad * 4 + rg);
    const int sbase = qb * 64 + wave * 16 + quad * 4;
    #pragma unroll
    for (int nt = 0; nt < 8; ++nt)
      #pragma unroll
      for (int rg = 0; rg < 4; ++rg) {
        float val = acco[nt][rg] / lr[rg];
        O[((size_t)(b * S_ + sbase + rg)) * D_ + h * DH_ + nt * 16 + r16] = f2bf(val);
      }
  }
#undef LOADKV
}

// ---------- layernorm: y = LN(a [+ a2] + res) * g + be ----------
__global__ __launch_bounds__(256) void ln_kernel(
    const float* __restrict__ a, const float* __restrict__ a2,
    const float* __restrict__ res,
    const float* __restrict__ g, const float* __restrict__ be,
    float* __restrict__ xf, u16* __restrict__ xb) {
  __shared__ float red[8];
  const int row = blockIdx.x, tid = threadIdx.x;
  const float4 va = ((const float4*)(a + (size_t)row * D_))[tid];
  const float4 vr = ((const float4*)(res + (size_t)row * D_))[tid];
  float4 v;
  v.x = va.x + vr.x; v.y = va.y + vr.y; v.z = va.z + vr.z; v.w = va.w + vr.w;
  if (a2) {
    const float4 v2 = ((const float4*)(a2 + (size_t)row * D_))[tid];
    v.x += v2.x; v.y += v2.y; v.z += v2.z; v.w += v2.w;
  }
  float s = v.x + v.y + v.z + v.w;
  float q = v.x * v.x + v.y * v.y + v.z * v.z + v.w * v.w;
  #pragma unroll
  for (int m = 1; m < 64; m <<= 1) {
    s += __shfl_xor(s, m);
    q += __shfl_xor(q, m);
  }
  const int wave = tid >> 6, lane = tid & 63;
  if (lane == 0) { red[wave] = s; red[4 + wave] = q; }
  __syncthreads();
  s = red[0] + red[1] + red[2] + red[3];
  q = red[4] + red[5] + red[6] + red[7];
  const float mu = s * (1.0f / D_);
  const float var = q * (1.0f / D_) - mu * mu;
  const float inv = rsqrtf(var + EPS_);
  const float4 gg = ((const float4*)g)[tid];
  const float4 bb = ((const float4*)be)[tid];
  float4 y;
  y.x = (v.x - mu) * inv * gg.x + bb.x;
  y.y = (v.y - mu) * inv * gg.y + bb.y;
  y.z = (v.z - mu) * inv * gg.z + bb.z;
  y.w = (v.w - mu) * inv * gg.w + bb.w;
  ((float4*)(xf + (size_t)row * D_))[tid] = y;
  if (xb) {
    ushort4 u;
    u.x = f2bf(y.x); u.y = f2bf(y.y); u.z = f2bf(y.z); u.w = f2bf(y.w);
    ((ushort4*)(xb + (size_t)row * D_))[tid] = u;
  }
}

extern "C" void kernel_launch(void* const* d_in, const int* in_sizes, int n_in,
                              void* d_out, int out_size, void* d_ws, size_t ws_size,
                              hipStream_t stream) {
  const float* src   = (const float*)d_in[0];
  const float* w_qkv = (const float*)d_in[1];
  const float* w_out = (const float*)d_in[2];
  const float* w1    = (const float*)d_in[3];
  const float* b1    = (const float*)d_in[4];
  const float* w2    = (const float*)d_in[5];
  const float* b2    = (const float*)d_in[6];
  const float* g1    = (const float*)d_in[7];
  const float* be1   = (const float*)d_in[8];
  const float* g2    = (const float*)d_in[9];
  const float* be2   = (const float*)d_in[10];
  float* out = (float*)d_out;

  char* ws = (char*)d_ws;
  size_t off = 0;
  auto alloc = [&](size_t bytes) -> void* {
    void* p = ws + off;
    off += (bytes + 255) & ~(size_t)255;
    return p;
  };
  u16* src_bf = (u16*)alloc((size_t)ROWS_ * D_ * 2);    // 16 MB @ 0
  u16* wqkvT  = (u16*)alloc((size_t)3 * D_ * D_ * 2);   //  6 MB @ 16M
  u16* woutT  = (u16*)alloc((size_t)D_ * D_ * 2);       //  2 MB @ 22M
  u16* w1T    = (u16*)alloc((size_t)DFF_ * D_ * 2);     //  8 MB @ 24M
  u16* w2T    = (u16*)alloc((size_t)D_ * DFF_ * 2);     //  8 MB @ 32M
  u16* qbuf   = (u16*)alloc((size_t)ROWS_ * D_ * 2);
  u16* kbuf   = (u16*)alloc((size_t)ROWS_ * D_ * 2);
  u16* vT     = (u16*)alloc((size_t)ROWS_ * D_ * 2);    // V written transposed
  u16* obuf   = (u16*)alloc((size_t)ROWS_ * D_ * 2);
  float* proj = (float*)alloc((size_t)ROWS_ * D_ * 4);
  float* xf   = (float*)alloc((size_t)ROWS_ * D_ * 4);
  u16* xb     = (u16*)alloc((size_t)ROWS_ * D_ * 2);
  u16* h1     = qbuf;   // alias: q,k,o dead before FFN1 writes
  float* ff   = proj;   // alias: proj dead after LN1
  // split-K partial: [ws, ws+32MB) = src_bf+wqkvT+woutT+w1T, all dead by FFN2
  float* ff2  = (float*)ws;

  const int GSMEM  = 131072;  // 256x256: 2 bufs x (A 32KB + B 32KB)
  const int GSMEM2 = 98304;   // 256x128: 2 bufs x (A 32KB + B 16KB)
  hipFuncSetAttribute((const void*)gemm256_kernel<2>, hipFuncAttributeMaxDynamicSharedMemorySize, GSMEM);
  hipFuncSetAttribute((const void*)gemm256_kernel<5>, hipFuncAttributeMaxDynamicSharedMemorySize, GSMEM);
  hipFuncSetAttribute((const void*)gemm256x128_kernel<0>, hipFuncAttributeMaxDynamicSharedMemorySize, GSMEM2);
  hipFuncSetAttribute((const void*)gemm256x128_kernel<1>, hipFuncAttributeMaxDynamicSharedMemorySize, GSMEM2);

  cast_bf16_kernel<<<2048, 256, 0, stream>>>(src, src_bf, ROWS_ * D_ / 4);
  transpose_cast_kernel<<<dim3(D_ / 32, 3 * D_ / 32), 256, 0, stream>>>(w_qkv, wqkvT, D_, 3 * D_);
  transpose_cast_kernel<<<dim3(D_ / 32, D_ / 32), 256, 0, stream>>>(w_out, woutT, D_, D_);
  transpose_cast_kernel<<<dim3(D_ / 32, DFF_ / 32), 256, 0, stream>>>(w1, w1T, D_, DFF_);
  transpose_cast_kernel<<<dim3(DFF_ / 32, D_ / 32), 256, 0, stream>>>(w2, w2T, DFF_, D_);

  // QKV: N=3072 -> 32x24 = 768 blocks; V blocks stored transposed (LDS-coalesced)
  gemm256x128_kernel<0><<<dim3(ROWS_ / 256, 3 * D_ / 128), 512, GSMEM2, stream>>>(
      src_bf, wqkvT, ROWS_, 3 * D_, D_, nullptr, nullptr, nullptr, qbuf, kbuf, vT);
  // attn: 512 pair-blocks, XCD-grouped + swizzled LDS + defer-max
  attn_kernel<<<512, 256, 0, stream>>>(qbuf, kbuf, vT, obuf);
  // out-proj: N=1024 -> 32x8 = 256 blocks
  gemm256x128_kernel<1><<<dim3(ROWS_ / 256, D_ / 128), 512, GSMEM2, stream>>>(
      obuf, woutT, ROWS_, D_, D_, proj, nullptr, nullptr, nullptr, nullptr, nullptr);
  ln_kernel<<<ROWS_, 256, 0, stream>>>(proj, nullptr, src, g1, be1, xf, xb);
  // FFN1: N=4096 -> 256x256 tile: 32x16 = 512 blocks
  gemm256_kernel<2><<<dim3(ROWS_ / 256, DFF_ / 256), 512, GSMEM, stream>>>(
      xb, w1T, ROWS_, DFF_, D_, D_, nullptr, nullptr, h1, b1, nullptr, nullptr, nullptr);
  // FFN2: 256x256 tile + split-K (K=4096 -> 2x2048): 32x4x2 = 256 blocks exact
  gemm256_kernel<5><<<dim3(ROWS_ / 256, D_ / 256, 2), 512, GSMEM, stream>>>(
      h1, w2T, ROWS_, D_, DFF_ / 2, DFF_, ff, ff2, nullptr, b2, nullptr, nullptr, nullptr);
  ln_kernel<<<ROWS_, 256, 0, stream>>>(ff, ff2, xf, g2, be2, out, nullptr);
}

// Round 10
// 463.300 us; speedup vs baseline: 1.1034x; 1.0247x over previous
//
#include <hip/hip_runtime.h>

typedef unsigned short u16;
typedef __attribute__((ext_vector_type(8))) short short8;
typedef __attribute__((ext_vector_type(4))) float float4v;

#define MFMA_BF16(a, b, c) __builtin_amdgcn_mfma_f32_16x16x32_bf16((a), (b), (c), 0, 0, 0)

#define B_ 4
#define S_ 2048
#define D_ 1024
#define H_ 8
#define DH_ 128
#define DFF_ 4096
#define EPS_ 1e-5f
#define ROWS_ (B_ * S_)   // 8192
#define CSCALE_ 0.12751672939502f  // (1/sqrt(128)) * log2(e), folded into Q

__device__ __forceinline__ u16 f2bf(float f) {
  union { float f; unsigned u; } x; x.f = f;
  unsigned r = x.u + 0x7fffu + ((x.u >> 16) & 1u);
  return (u16)(r >> 16);
}

typedef __attribute__((address_space(1))) const unsigned int guint;
typedef __attribute__((address_space(3))) unsigned int luint;
__device__ __forceinline__ void gl2lds16(const u16* g, u16* l) {
  // each lane: 16B from its own g -> wave-uniform lds base + lane*16
  __builtin_amdgcn_global_load_lds((guint*)g, (luint*)l, 16, 0, 0);
}

// ---------- merged prep: cast src -> bf16 + 4 weight transposes ----------
// One launch replaces 5 (each underfilled the GPU and paid a launch gap).
// blocks [0,2048): grid-stride cast of src (float4 granularity)
// blocks [2048,...): 32x32 transpose-cast tiles routed by block-id range.
__global__ __launch_bounds__(256) void prep_kernel(
    const float* __restrict__ src, u16* __restrict__ src_bf,
    const float* __restrict__ w_qkv, u16* __restrict__ wqkvT,
    const float* __restrict__ w_out, u16* __restrict__ woutT,
    const float* __restrict__ w1, u16* __restrict__ w1T,
    const float* __restrict__ w2, u16* __restrict__ w2T) {
  __shared__ float t[32][33];
  int bid = blockIdx.x;
  if (bid < 2048) {
    const int n4 = ROWS_ * D_ / 4;
    int i = bid * 256 + threadIdx.x;
    for (; i < n4; i += 2048 * 256) {
      float4 v = ((const float4*)src)[i];
      ushort4 u;
      u.x = f2bf(v.x); u.y = f2bf(v.y); u.z = f2bf(v.z); u.w = f2bf(v.w);
      ((ushort4*)src_bf)[i] = u;
    }
    return;
  }
  bid -= 2048;
  const float* in; u16* outp; int K, N;
  if (bid < 3072)       { in = w_qkv; outp = wqkvT; K = D_;   N = 3 * D_; }
  else if (bid < 4096)  { bid -= 3072; in = w_out; outp = woutT; K = D_;   N = D_; }
  else if (bid < 8192)  { bid -= 4096; in = w1;    outp = w1T;   K = D_;   N = DFF_; }
  else                  { bid -= 8192; in = w2;    outp = w2T;   K = DFF_; N = D_; }
  const int nxB = K / 32;
  const int k0 = (bid % nxB) * 32, n0 = (bid / nxB) * 32;
  const int tx = threadIdx.x & 31, ty = threadIdx.x >> 5;  // 32x8 threads
  #pragma unroll
  for (int i = 0; i < 4; ++i)
    t[ty + 8 * i][tx] = in[(size_t)(k0 + ty + 8 * i) * N + n0 + tx];
  __syncthreads();
  #pragma unroll
  for (int i = 0; i < 4; ++i)
    outp[(size_t)(n0 + ty + 8 * i) * K + k0 + tx] = f2bf(t[tx][ty + 8 * i]);
}

// ============== bf16 MFMA GEMM, 256x256 tile, 8-phase schedule ==============
// C[M,N] = A[M,K] @ Bt[N,K]^T.  512 thr = 8 waves (2M x 4N); per-wave 128x64.
// lda = row stride (elements) of A and Bt.  MODE 2: +bias, relu, bf16 out.
template <int MODE>
__global__ __launch_bounds__(512, 2) void gemm256_kernel(
    const u16* __restrict__ A, const u16* __restrict__ Bt,
    const int M, const int N, const int K, const int lda,
    float* __restrict__ outF, float* __restrict__ outF2,
    u16* __restrict__ outH, const float* __restrict__ bias,
    u16* __restrict__ qo, u16* __restrict__ ko, u16* __restrict__ vo) {
  extern __shared__ u16 smem[];
  u16* At  = smem;                  // [2][256][64] permuted rows, swizzled chunks
  u16* Bts = smem + 2 * 256 * 64;   // [2][256][64] linear rows, swizzled chunks
  const int tid = threadIdx.x;
  const int lane = tid & 63, wave = tid >> 6;
  const int quad = lane >> 4, r16 = lane & 15;
  const int halfw = wave >> 2;          // output row half (0/1)
  const int wn = (wave & 3) * 64;       // output col offset in tile
  const int m0 = blockIdx.x * 256, n0 = blockIdx.y * 256;
  const int NT = K >> 6;

  const int rowin = wave * 8 + (lane >> 3);   // 0..63 within unit
  const int sc = lane & 7;
  const int shalf = rowin >> 5, srr = rowin & 31;

  const u16* Asrc[4];
  const u16* Bsrc[4];
  #pragma unroll
  for (int u = 0; u < 4; ++u) {
    const int ra = shalf * 128 + u * 32 + srr;   // logical A row of unit u
    Asrc[u] = A + (size_t)(m0 + ra) * lda + (sc ^ (ra & 7)) * 8;
    const int rb = u * 64 + rowin;               // logical B row of unit u
    Bsrc[u] = Bt + (size_t)(n0 + rb) * lda + (sc ^ (rb & 7)) * 8;
  }

  float4v acc[8][4];
  #pragma unroll
  for (int i = 0; i < 8; ++i)
    #pragma unroll
    for (int j = 0; j < 4; ++j) acc[i][j] = (float4v)0.0f;

#define STAGE_A(t, u) gl2lds16(Asrc[u] + (t) * 64, At  + ((t) & 1) * 16384 + (u) * 4096 + wave * 512)
#define STAGE_B(t, u) gl2lds16(Bsrc[u] + (t) * 64, Bts + ((t) & 1) * 16384 + (u) * 4096 + wave * 512)

  STAGE_B(0, 0); STAGE_B(0, 1); STAGE_B(0, 2); STAGE_B(0, 3);
  STAGE_A(0, 0); STAGE_A(0, 1); STAGE_A(0, 2); STAGE_A(0, 3);
  if (NT > 1) {
    STAGE_B(1, 0); STAGE_B(1, 1); STAGE_B(1, 2); STAGE_B(1, 3);
    STAGE_A(1, 0); STAGE_A(1, 1);
    asm volatile("s_waitcnt vmcnt(6)" ::: "memory");
  } else {
    asm volatile("s_waitcnt vmcnt(0)" ::: "memory");
  }
  __builtin_amdgcn_s_barrier();

  for (int kt = 0; kt < NT; ++kt) {
    const u16* Ab = At + (kt & 1) * 16384;
    const u16* Bb = Bts + (kt & 1) * 16384;
    short8 bfr[4][2];
    #pragma unroll
    for (int q = 0; q < 4; ++q) {
      if (q == 0) {
        #pragma unroll
        for (int j = 0; j < 4; ++j)
          #pragma unroll
          for (int s = 0; s < 2; ++s)
            bfr[j][s] = *(const short8*)(Bb + (wn + j * 16 + r16) * 64 +
                                         (((s * 4 + quad) ^ (r16 & 7)) * 8));
      }
      short8 af[2][2];
      #pragma unroll
      for (int di = 0; di < 2; ++di)
        #pragma unroll
        for (int s = 0; s < 2; ++s)
          af[di][s] = *(const short8*)(Ab + (q * 64 + halfw * 32 + di * 16 + r16) * 64 +
                                       (((s * 4 + quad) ^ (r16 & 7)) * 8));
      if (q == 0)      { if (kt + 1 < NT) { STAGE_A(kt + 1, 2); STAGE_A(kt + 1, 3); } }
      else if (q == 1) { if (kt + 2 < NT) { STAGE_B(kt + 2, 0); STAGE_B(kt + 2, 1); } }
      else if (q == 2) { if (kt + 2 < NT) { STAGE_B(kt + 2, 2); STAGE_B(kt + 2, 3); } }
      else             { if (kt + 2 < NT) { STAGE_A(kt + 2, 0); STAGE_A(kt + 2, 1); } }
      __builtin_amdgcn_s_barrier();
      asm volatile("s_waitcnt lgkmcnt(0)" ::: "memory");
      __builtin_amdgcn_s_setprio(1);
      #pragma unroll
      for (int j = 0; j < 4; ++j) {
        acc[2 * q][j]     = MFMA_BF16(af[0][0], bfr[j][0], acc[2 * q][j]);
        acc[2 * q][j]     = MFMA_BF16(af[0][1], bfr[j][1], acc[2 * q][j]);
        acc[2 * q + 1][j] = MFMA_BF16(af[1][0], bfr[j][0], acc[2 * q + 1][j]);
        acc[2 * q + 1][j] = MFMA_BF16(af[1][1], bfr[j][1], acc[2 * q + 1][j]);
      }
      __builtin_amdgcn_s_setprio(0);
      if (q == 3) {
        if (kt + 2 < NT)      { asm volatile("s_waitcnt vmcnt(6)" ::: "memory"); }
        else if (kt + 1 < NT) { asm volatile("s_waitcnt vmcnt(0)" ::: "memory"); }
      }
      __builtin_amdgcn_s_barrier();
    }
  }
#undef STAGE_A
#undef STAGE_B

  #pragma unroll
  for (int i = 0; i < 8; ++i) {
    const int rowb = m0 + halfw * 128 + i * 16 + quad * 4;
    #pragma unroll
    for (int j = 0; j < 4; ++j) {
      const int col = n0 + wn + j * 16 + r16;
      #pragma unroll
      for (int rg = 0; rg < 4; ++rg) {
        float val = acc[i][j][rg];
        const int r = rowb + rg;
        if (MODE == 2) {
          val += bias[col];
          val = fmaxf(val, 0.0f);
          outH[(size_t)r * N + col] = f2bf(val);
        } else {
          outF[(size_t)r * N + col] = val;
        }
      }
    }
  }
}

// ============ bf16 MFMA GEMM, 256x128 tile, phase-pipelined ============
// 512 thr = 8 waves (4M x 2N); per-wave 64x64 output, acc[4][4].
// MODE 0: q/k scatter bf16; V blocks (n0>=2048) transposed via LDS ->
//         coalesced vT[bh][dh][s] stores.  MODE 1: fp32; MODE 3: +bias fp32.
template <int MODE>
__global__ __launch_bounds__(512, 2) void gemm256x128_kernel(
    const u16* __restrict__ A, const u16* __restrict__ Bt,
    const int M, const int N, const int K,
    float* __restrict__ outF, u16* __restrict__ outH, const float* __restrict__ bias,
    u16* __restrict__ qo, u16* __restrict__ ko, u16* __restrict__ vo) {
  extern __shared__ u16 smem[];
  u16* At  = smem;                  // [2][256][64]
  u16* Bts = smem + 2 * 256 * 64;   // [2][128][64]
  const int tid = threadIdx.x;
  const int lane = tid & 63, wave = tid >> 6;
  const int quad = lane >> 4, r16 = lane & 15;
  const int w64 = wave >> 1;            // output row quarter (0..3)
  const int wn = (wave & 1) * 64;       // output col offset in tile
  const int m0 = blockIdx.x * 256, n0 = blockIdx.y * 128;
  const int NT = K >> 6;

  const int rowin = wave * 8 + (lane >> 3);   // 0..63 within 64-row unit
  const int sc = lane & 7;

  const u16* Asrc[4];
  const u16* Bsrc[2];
  #pragma unroll
  for (int u = 0; u < 4; ++u) {
    const int ra = ((u & 1) * 2 + (rowin >> 5)) * 64 + (u >> 1) * 32 + (rowin & 31);
    Asrc[u] = A + (size_t)(m0 + ra) * K + (sc ^ (ra & 7)) * 8;
  }
  #pragma unroll
  for (int u = 0; u < 2; ++u) {
    const int rb = u * 64 + rowin;
    Bsrc[u] = Bt + (size_t)(n0 + rb) * K + (sc ^ (rb & 7)) * 8;
  }

  float4v acc[4][4];
  #pragma unroll
  for (int i = 0; i < 4; ++i)
    #pragma unroll
    for (int j = 0; j < 4; ++j) acc[i][j] = (float4v)0.0f;

#define STAGE_A(t, u) gl2lds16(Asrc[u] + (t) * 64, At  + ((t) & 1) * 16384 + (u) * 4096 + wave * 512)
#define STAGE_B(t, u) gl2lds16(Bsrc[u] + (t) * 64, Bts + ((t) & 1) * 8192 + (u) * 4096 + wave * 512)

  STAGE_B(0, 0); STAGE_B(0, 1); STAGE_A(0, 0); STAGE_A(0, 1);
  STAGE_A(0, 2); STAGE_A(0, 3);
  STAGE_B(1, 0); STAGE_B(1, 1); STAGE_A(1, 0); STAGE_A(1, 1);
  asm volatile("s_waitcnt vmcnt(6)" ::: "memory");
  __builtin_amdgcn_s_barrier();

  for (int kt = 0; kt < NT; ++kt) {
    const u16* Ab = At + (kt & 1) * 16384;
    const u16* Bb = Bts + (kt & 1) * 8192;
    short8 bfr[4][2];
    #pragma unroll
    for (int j = 0; j < 4; ++j)
      #pragma unroll
      for (int s = 0; s < 2; ++s)
        bfr[j][s] = *(const short8*)(Bb + (wn + j * 16 + r16) * 64 +
                                     (((s * 4 + quad) ^ (r16 & 7)) * 8));
    {
      short8 af[2][2];
      #pragma unroll
      for (int di = 0; di < 2; ++di)
        #pragma unroll
        for (int s = 0; s < 2; ++s)
          af[di][s] = *(const short8*)(Ab + (w64 * 32 + di * 16 + r16) * 64 +
                                       (((s * 4 + quad) ^ (r16 & 7)) * 8));
      if (kt + 1 < NT) { STAGE_A(kt + 1, 2); STAGE_A(kt + 1, 3); }
      __builtin_amdgcn_s_barrier();
      asm volatile("s_waitcnt lgkmcnt(0)" ::: "memory");
      __builtin_amdgcn_s_setprio(1);
      #pragma unroll
      for (int j = 0; j < 4; ++j) {
        acc[0][j] = MFMA_BF16(af[0][0], bfr[j][0], acc[0][j]);
        acc[0][j] = MFMA_BF16(af[0][1], bfr[j][1], acc[0][j]);
        acc[1][j] = MFMA_BF16(af[1][0], bfr[j][0], acc[1][j]);
        acc[1][j] = MFMA_BF16(af[1][1], bfr[j][1], acc[1][j]);
      }
      __builtin_amdgcn_s_setprio(0);
      if (kt + 1 < NT) { asm volatile("s_waitcnt vmcnt(6)" ::: "memory"); }
      else             { asm volatile("s_waitcnt vmcnt(0)" ::: "memory"); }
      __builtin_amdgcn_s_barrier();
    }
    {
      short8 af[2][2];
      #pragma unroll
      for (int di = 0; di < 2; ++di)
        #pragma unroll
        for (int s = 0; s < 2; ++s)
          af[di][s] = *(const short8*)(Ab + (128 + w64 * 32 + di * 16 + r16) * 64 +
                                       (((s * 4 + quad) ^ (r16 & 7)) * 8));
      if (kt + 2 < NT) {
        STAGE_B(kt + 2, 0); STAGE_B(kt + 2, 1);
        STAGE_A(kt + 2, 0); STAGE_A(kt + 2, 1);
      }
      __builtin_amdgcn_s_barrier();
      asm volatile("s_waitcnt lgkmcnt(0)" ::: "memory");
      __builtin_amdgcn_s_setprio(1);
      #pragma unroll
      for (int j = 0; j < 4; ++j) {
        acc[2][j] = MFMA_BF16(af[0][0], bfr[j][0], acc[2][j]);
        acc[2][j] = MFMA_BF16(af[0][1], bfr[j][1], acc[2][j]);
        acc[3][j] = MFMA_BF16(af[1][0], bfr[j][0], acc[3][j]);
        acc[3][j] = MFMA_BF16(af[1][1], bfr[j][1], acc[3][j]);
      }
      __builtin_amdgcn_s_setprio(0);
      if (kt + 1 < NT) {
        if (kt + 2 < NT) { asm volatile("s_waitcnt vmcnt(6)" ::: "memory"); }
        else             { asm volatile("s_waitcnt vmcnt(2)" ::: "memory"); }
      }
      __builtin_amdgcn_s_barrier();
    }
  }
#undef STAGE_A
#undef STAGE_B

  if (MODE == 0 && n0 >= 2 * D_) {
    // V block: covers exactly vT[bh][0..127][s0..s0+255]. Stage [dh][s] in
    // LDS (pad 260), then coalesced short8 stores (512B runs per dh row).
    u16* vlds = smem;   // 128*260*2 = 66560 B <= 96 KiB
    __syncthreads();
    #pragma unroll
    for (int i = 0; i < 4; ++i) {
      const int sl = w64 * 64 + i * 16 + quad * 4;
      #pragma unroll
      for (int j = 0; j < 4; ++j) {
        const int dh = wn + j * 16 + r16;
        #pragma unroll
        for (int rg = 0; rg < 4; ++rg)
          vlds[dh * 260 + sl + rg] = f2bf(acc[i][j][rg]);
      }
    }
    __syncthreads();
    const int b = m0 >> 11, s0 = m0 & 2047;
    const int h = (n0 - 2 * D_) >> 7;
    u16* vbase = vo + (size_t)(b * H_ + h) * DH_ * S_ + s0;
    #pragma unroll
    for (int p = 0; p < 8; ++p) {
      const int dh = p * 16 + (tid >> 5);
      const int ss = (tid & 31) * 8;
      short8 v8 = *(const short8*)&vlds[dh * 260 + ss];
      *(short8*)(vbase + (size_t)dh * S_ + ss) = v8;
    }
    return;
  }

  #pragma unroll
  for (int i = 0; i < 4; ++i) {
    const int rowb = m0 + w64 * 64 + i * 16 + quad * 4;
    #pragma unroll
    for (int j = 0; j < 4; ++j) {
      const int col = n0 + wn + j * 16 + r16;
      #pragma unroll
      for (int rg = 0; rg < 4; ++rg) {
        float val = acc[i][j][rg];
        const int r = rowb + rg;
        if (MODE == 0) {
          const int part = col >> 10, cc = col & 1023;
          const int h = cc >> 7, dh = cc & 127;
          const int b = r >> 11, s = r & 2047;
          if (part == 0) {
            qo[((size_t)(b * H_ + h) * S_ + s) * DH_ + dh] = f2bf(val * CSCALE_);
          } else {
            ko[((size_t)(b * H_ + h) * S_ + s) * DH_ + dh] = f2bf(val);
          }
        } else if (MODE == 1) {
          outF[(size_t)r * N + col] = val;
        } else {
          val += bias[col];
          outF[(size_t)r * N + col] = val;
        }
      }
    }
  }
}

// ---------------- flash causal attention (S^T formulation) ----------------
// 512 pair-blocks, XCD-grouped (FETCH 259->25MB).  Async-STAGE (T14) +
// defer-max (T13).  T2 XOR-swizzle on Ks/Vt/Pw (bank-conflict 10.3M -> ~0).
__global__ __launch_bounds__(256) void attn_kernel(
    const u16* __restrict__ Q, const u16* __restrict__ Kg,
    const u16* __restrict__ Vtg, u16* __restrict__ O) {
  __shared__ u16 Ks[64][128];     // [key][d]    swizzled
  __shared__ u16 Vt[128][64];     // [d][key]    swizzled
  __shared__ u16 Pw[4][16][64];   // per-wave P  swizzled
  const int tid = threadIdx.x;
  const int lane = tid & 63, wave = tid >> 6;
  const int quad = lane >> 4, r16 = lane & 15;
  const int id = blockIdx.x;                    // 0..511
  const int bh = (id & 7) * 4 + (id >> 7);      // 16 pair-blocks of bh per XCD
  const int pairIdx = (id >> 3) & 15;           // 0..15
  const size_t base = (size_t)bh * S_ * DH_;
  const size_t vtb = (size_t)bh * DH_ * S_;
  const int b = bh >> 3, h = bh & 7;

  const u16* kg0 = Kg + base + (size_t)(tid >> 4) * DH_ + (tid & 15) * 8;
  u16* ksl = &Ks[tid >> 4][((tid & 15) ^ ((tid >> 4) & 7)) * 8];
  const u16* vg0 = Vtg + vtb + (size_t)(tid >> 3) * S_ + (tid & 7) * 8;
  u16* vtl = &Vt[tid >> 3][((tid & 7) ^ ((tid >> 3) & 7)) * 8];

  short8 rk[4], rv[4];
#define LOADKV(kb_)                                                        \
  do {                                                                     \
    _Pragma("unroll")                                                      \
    for (int i_ = 0; i_ < 4; ++i_)                                         \
      rk[i_] = *(const short8*)(kg0 + (size_t)((kb_) * 64 + i_ * 16) * DH_); \
    _Pragma("unroll")                                                      \
    for (int i_ = 0; i_ < 4; ++i_)                                         \
      rv[i_] = *(const short8*)(vg0 + (size_t)i_ * 32 * S_ + (kb_) * 64);  \
  } while (0)

  for (int half = 0; half < 2; ++half) {
    const int qb = (half == 0) ? pairIdx : 31 - pairIdx;
    const int qr = qb * 64 + wave * 16 + r16;  // this lane's q-row (as B-col)

    short8 aq[4];
    #pragma unroll
    for (int ks = 0; ks < 4; ++ks)
      aq[ks] = *(const short8*)(Q + base + (size_t)qr * DH_ + ks * 32 + quad * 8);

    float4v acco[8];
    #pragma unroll
    for (int i = 0; i < 8; ++i) acco[i] = (float4v)0.0f;
    float m_q = -1e30f, l_q = 0.0f;  // per q=r16, replicated across quads

    LOADKV(0);  // prefetch tile 0 for this half

    for (int kb = 0; kb <= qb; ++kb) {
      __syncthreads();   // prior iter's LDS reads done before overwrite
      #pragma unroll
      for (int i = 0; i < 4; ++i) *(short8*)(ksl + i * 16 * 128) = rk[i];
      #pragma unroll
      for (int i = 0; i < 4; ++i) *(short8*)(vtl + i * 32 * 64) = rv[i];
      __syncthreads();
      if (kb < qb) LOADKV(kb + 1);  // prefetch next; latency hides under compute

      // S^T tile: rows = keys (64), cols = q (16/wave). A = K, B = Qfrag.
      float4v accs[4];
      #pragma unroll
      for (int t = 0; t < 4; ++t) accs[t] = (float4v)0.0f;
      #pragma unroll
      for (int ks = 0; ks < 4; ++ks) {
        #pragma unroll
        for (int t = 0; t < 4; ++t) {
          short8 ak = *(const short8*)&Ks[t * 16 + r16][((ks * 4 + quad) ^ (r16 & 7)) * 8];
          accs[t] = MFMA_BF16(ak, aq[ks], accs[t]);
        }
      }
      if (kb == qb) {
        #pragma unroll
        for (int t = 0; t < 4; ++t)
          #pragma unroll
          for (int rg = 0; rg < 4; ++rg) {
            int kc = kb * 64 + t * 16 + quad * 4 + rg;
            if (kc > qr) accs[t][rg] = -1e30f;
          }
      }
      // online softmax: lane owns q=r16; 16 local scores + 2 shfl (quads)
      float mv = accs[0][0];
      #pragma unroll
      for (int t = 0; t < 4; ++t)
        #pragma unroll
        for (int rg = 0; rg < 4; ++rg) mv = fmaxf(mv, accs[t][rg]);
      mv = fmaxf(mv, __shfl_xor(mv, 16));
      mv = fmaxf(mv, __shfl_xor(mv, 32));
      // defer-max (T13): skip O-rescale when tile max within THR of running
      // max (P bounded by 2^8, fp32-safe). Wave-uniform branch.
      const bool nore = __all(mv <= m_q + 8.0f) != 0;
      const float mnew = nore ? m_q : fmaxf(m_q, mv);
      float alpha = 1.0f;
      if (!nore) alpha = __builtin_amdgcn_exp2f(m_q - mnew);
      float s0 = 0.0f;
      #pragma unroll
      for (int t = 0; t < 4; ++t)
        #pragma unroll
        for (int rg = 0; rg < 4; ++rg) {
          float p = __builtin_amdgcn_exp2f(accs[t][rg] - mnew);
          accs[t][rg] = p;
          s0 += p;
        }
      s0 += __shfl_xor(s0, 16);
      s0 += __shfl_xor(s0, 32);
      l_q = nore ? (l_q + s0) : (l_q * alpha + s0);
      m_q = mnew;

      // P^T -> Pw[q][key] packed b64; swizzled 16B chunk = (2t+(quad>>1))^(r16&7),
      // 8B half = quad&1
      #pragma unroll
      for (int t = 0; t < 4; ++t) {
        union { float f; unsigned u; } c0, c1, c2, c3;
        c0.f = accs[t][0]; c1.f = accs[t][1]; c2.f = accs[t][2]; c3.f = accs[t][3];
        uint2 pk;
        pk.x = ((c0.u + 0x8000u) >> 16) | ((c1.u + 0x8000u) & 0xffff0000u);
        pk.y = ((c2.u + 0x8000u) >> 16) | ((c3.u + 0x8000u) & 0xffff0000u);
        *(uint2*)&Pw[wave][r16][(((t * 2 + (quad >> 1)) ^ (r16 & 7)) * 8) + (quad & 1) * 4] = pk;
      }
      if (!nore) {
        float al[4];
        #pragma unroll
        for (int rg = 0; rg < 4; ++rg) al[rg] = __shfl(alpha, quad * 4 + rg);
        #pragma unroll
        for (int nt = 0; nt < 8; ++nt)
          #pragma unroll
          for (int rg = 0; rg < 4; ++rg) acco[nt][rg] *= al[rg];
      }
      asm volatile("s_waitcnt lgkmcnt(0)" ::: "memory");
      // O += P @ V
      #pragma unroll
      for (int ks2 = 0; ks2 < 2; ++ks2) {
        short8 ap = *(const short8*)&Pw[wave][r16][((ks2 * 4 + quad) ^ (r16 & 7)) * 8];
        #pragma unroll
        for (int nt = 0; nt < 8; ++nt) {
          short8 bv = *(const short8*)&Vt[nt * 16 + r16][((ks2 * 4 + quad) ^ (r16 & 7)) * 8];
          acco[nt] = MFMA_BF16(ap, bv, acco[nt]);
        }
      }
    }

    // epilogue: O rows q=quad*4+rg, cols d=nt*16+r16
    float lr[4];
    #pragma unroll
    for (int rg = 0; rg < 4; ++rg) lr[rg] = __shfl(l_q, quad * 4 + rg);
    const int sbase = qb * 64 + wave * 16 + quad * 4;
    #pragma unroll
    for (int nt = 0; nt < 8; ++nt)
      #pragma unroll
      for (int rg = 0; rg < 4; ++rg) {
        float val = acco[nt][rg] / lr[rg];
        O[((size_t)(b * S_ + sbase + rg)) * D_ + h * DH_ + nt * 16 + r16] = f2bf(val);
      }
  }
#undef LOADKV
}

// ---------- layernorm: y = LN(a [+ a2] + res) * g + be ----------
__global__ __launch_bounds__(256) void ln_kernel(
    const float* __restrict__ a, const float* __restrict__ a2,
    const float* __restrict__ res,
    const float* __restrict__ g, const float* __restrict__ be,
    float* __restrict__ xf, u16* __restrict__ xb) {
  __shared__ float red[8];
  const int row = blockIdx.x, tid = threadIdx.x;
  const float4 va = ((const float4*)(a + (size_t)row * D_))[tid];
  const float4 vr = ((const float4*)(res + (size_t)row * D_))[tid];
  float4 v;
  v.x = va.x + vr.x; v.y = va.y + vr.y; v.z = va.z + vr.z; v.w = va.w + vr.w;
  if (a2) {
    const float4 v2 = ((const float4*)(a2 + (size_t)row * D_))[tid];
    v.x += v2.x; v.y += v2.y; v.z += v2.z; v.w += v2.w;
  }
  float s = v.x + v.y + v.z + v.w;
  float q = v.x * v.x + v.y * v.y + v.z * v.z + v.w * v.w;
  #pragma unroll
  for (int m = 1; m < 64; m <<= 1) {
    s += __shfl_xor(s, m);
    q += __shfl_xor(q, m);
  }
  const int wave = tid >> 6, lane = tid & 63;
  if (lane == 0) { red[wave] = s; red[4 + wave] = q; }
  __syncthreads();
  s = red[0] + red[1] + red[2] + red[3];
  q = red[4] + red[5] + red[6] + red[7];
  const float mu = s * (1.0f / D_);
  const float var = q * (1.0f / D_) - mu * mu;
  const float inv = rsqrtf(var + EPS_);
  const float4 gg = ((const float4*)g)[tid];
  const float4 bb = ((const float4*)be)[tid];
  float4 y;
  y.x = (v.x - mu) * inv * gg.x + bb.x;
  y.y = (v.y - mu) * inv * gg.y + bb.y;
  y.z = (v.z - mu) * inv * gg.z + bb.z;
  y.w = (v.w - mu) * inv * gg.w + bb.w;
  ((float4*)(xf + (size_t)row * D_))[tid] = y;
  if (xb) {
    ushort4 u;
    u.x = f2bf(y.x); u.y = f2bf(y.y); u.z = f2bf(y.z); u.w = f2bf(y.w);
    ((ushort4*)(xb + (size_t)row * D_))[tid] = u;
  }
}

extern "C" void kernel_launch(void* const* d_in, const int* in_sizes, int n_in,
                              void* d_out, int out_size, void* d_ws, size_t ws_size,
                              hipStream_t stream) {
  const float* src   = (const float*)d_in[0];
  const float* w_qkv = (const float*)d_in[1];
  const float* w_out = (const float*)d_in[2];
  const float* w1    = (const float*)d_in[3];
  const float* b1    = (const float*)d_in[4];
  const float* w2    = (const float*)d_in[5];
  const float* b2    = (const float*)d_in[6];
  const float* g1    = (const float*)d_in[7];
  const float* be1   = (const float*)d_in[8];
  const float* g2    = (const float*)d_in[9];
  const float* be2   = (const float*)d_in[10];
  float* out = (float*)d_out;

  char* ws = (char*)d_ws;
  size_t off = 0;
  auto alloc = [&](size_t bytes) -> void* {
    void* p = ws + off;
    off += (bytes + 255) & ~(size_t)255;
    return p;
  };
  u16* src_bf = (u16*)alloc((size_t)ROWS_ * D_ * 2);
  u16* wqkvT  = (u16*)alloc((size_t)3 * D_ * D_ * 2);   // [3072][1024]
  u16* woutT  = (u16*)alloc((size_t)D_ * D_ * 2);
  u16* w1T    = (u16*)alloc((size_t)DFF_ * D_ * 2);     // [4096][1024]
  u16* w2T    = (u16*)alloc((size_t)D_ * DFF_ * 2);     // [1024][4096]
  u16* qbuf   = (u16*)alloc((size_t)ROWS_ * D_ * 2);
  u16* kbuf   = (u16*)alloc((size_t)ROWS_ * D_ * 2);
  u16* vT     = (u16*)alloc((size_t)ROWS_ * D_ * 2);    // V written transposed
  u16* obuf   = (u16*)alloc((size_t)ROWS_ * D_ * 2);
  float* proj = (float*)alloc((size_t)ROWS_ * D_ * 4);
  float* xf   = (float*)alloc((size_t)ROWS_ * D_ * 4);
  u16* xb     = (u16*)alloc((size_t)ROWS_ * D_ * 2);
  u16* h1     = qbuf;   // alias: q,k,o dead before FFN1 writes
  float* ff   = proj;   // alias: proj dead after LN1

  const int GSMEM  = 131072;  // 256x256: 2 bufs x (A 32KB + B 32KB)
  const int GSMEM2 = 98304;   // 256x128: 2 bufs x (A 32KB + B 16KB)
  hipFuncSetAttribute((const void*)gemm256_kernel<2>, hipFuncAttributeMaxDynamicSharedMemorySize, GSMEM);
  hipFuncSetAttribute((const void*)gemm256x128_kernel<0>, hipFuncAttributeMaxDynamicSharedMemorySize, GSMEM2);
  hipFuncSetAttribute((const void*)gemm256x128_kernel<1>, hipFuncAttributeMaxDynamicSharedMemorySize, GSMEM2);
  hipFuncSetAttribute((const void*)gemm256x128_kernel<3>, hipFuncAttributeMaxDynamicSharedMemorySize, GSMEM2);

  // merged prep: cast (2048 blocks) + 4 weight transposes (12288 blocks)
  prep_kernel<<<14336, 256, 0, stream>>>(src, src_bf, w_qkv, wqkvT,
                                         w_out, woutT, w1, w1T, w2, w2T);

  // QKV: N=3072 -> 32x24 = 768 blocks; V blocks stored transposed (LDS-coalesced)
  gemm256x128_kernel<0><<<dim3(ROWS_ / 256, 3 * D_ / 128), 512, GSMEM2, stream>>>(
      src_bf, wqkvT, ROWS_, 3 * D_, D_, nullptr, nullptr, nullptr, qbuf, kbuf, vT);
  // attn: 512 pair-blocks, XCD-grouped + swizzled LDS + defer-max
  attn_kernel<<<512, 256, 0, stream>>>(qbuf, kbuf, vT, obuf);
  // out-proj: N=1024 -> 32x8 = 256 blocks
  gemm256x128_kernel<1><<<dim3(ROWS_ / 256, D_ / 128), 512, GSMEM2, stream>>>(
      obuf, woutT, ROWS_, D_, D_, proj, nullptr, nullptr, nullptr, nullptr, nullptr);
  ln_kernel<<<ROWS_, 256, 0, stream>>>(proj, nullptr, src, g1, be1, xf, xb);
  // FFN1: N=4096 -> 256x256 tile: 32x16 = 512 blocks
  gemm256_kernel<2><<<dim3(ROWS_ / 256, DFF_ / 256), 512, GSMEM, stream>>>(
      xb, w1T, ROWS_, DFF_, D_, D_, nullptr, nullptr, h1, b1, nullptr, nullptr, nullptr);
  // FFN2: N=1024, K=4096 -> x128 plain (measured best net incl. LN2)
  gemm256x128_kernel<3><<<dim3(ROWS_ / 256, D_ / 128), 512, GSMEM2, stream>>>(
      h1, w2T, ROWS_, D_, DFF_, ff, nullptr, b2, nullptr, nullptr, nullptr);
  ln_kernel<<<ROWS_, 256, 0, stream>>>(ff, nullptr, xf, g2, be2, out, nullptr);
}